// Round 3
// baseline (372.460 us; speedup 1.0000x reference)
//
#include <hip/hip_runtime.h>
#include <hip/hip_bf16.h>

// Shapes: B=2, L=1024, D_MODEL=1024, D_INNER=2048, D_STATE=16, D_CONV=4, DT_RANK=64
#define BATCH 2
#define SEQLEN 1024
#define DMODEL 1024
#define DINNER 2048
#define DSTATE 16
#define DTRANK 64
#define ROWS (BATCH * SEQLEN) // 2048
#define LOG2E 1.44269504088896340736f

using bf16 = __hip_bfloat16;
typedef __bf16 bf16x8 __attribute__((ext_vector_type(8)));
typedef float f32x4 __attribute__((ext_vector_type(4)));
typedef unsigned short us8 __attribute__((ext_vector_type(8)));

__device__ __forceinline__ float to_f(float x) { return x; }
__device__ __forceinline__ float to_f(bf16 x) { return __bfloat162float(x); }

__device__ __forceinline__ float fexp2(float x) { return __builtin_amdgcn_exp2f(x); }

__device__ __forceinline__ float bfu(unsigned short u) {
    union { unsigned int i; float f; } v;
    v.i = ((unsigned int)u) << 16;
    return v.f;
}

__device__ __forceinline__ unsigned short bf_bits(float x) {
    bf16 h = __float2bfloat16(x);
    union { bf16 b; unsigned short u; } cv;
    cv.b = h;
    return cv.u;
}

__device__ __forceinline__ float softplus_f(float x) {
    return fmaxf(x, 0.f) + log1pf(expf(-fabsf(x)));
}
// fast silu
__device__ __forceinline__ float silu_f(float x) {
    return x * __builtin_amdgcn_rcpf(1.f + fexp2(-x * LOG2E));
}

// DPP row_shr move (within 16-lane row); invalid source lanes contribute 0.
template <int CTRL>
__device__ __forceinline__ float dpp_shr(float x) {
    int r = __builtin_amdgcn_update_dpp(0, __builtin_bit_cast(int, x), CTRL, 0xF, 0xF, false);
    return __builtin_bit_cast(float, r);
}
// 16-lane reduce: lane (n==15) of each row16 holds the sum.
__device__ __forceinline__ float row16_sum_to_lane15(float p) {
    p += dpp_shr<0x111>(p);  // row_shr:1
    p += dpp_shr<0x112>(p);  // row_shr:2
    p += dpp_shr<0x114>(p);  // row_shr:4
    p += dpp_shr<0x118>(p);  // row_shr:8
    return p;
}

// async 16B global -> LDS
__device__ __forceinline__ void gload16(const void* g, void* l) {
    __builtin_amdgcn_global_load_lds(
        (const __attribute__((address_space(1))) void*)g,
        (__attribute__((address_space(3))) void*)l, 16, 0, 0);
}

// ---------- prep: block 0 = dtype detect; blocks 1.. zero xd ----------
__global__ __launch_bounds__(256) void prep_kernel(const unsigned short* hs, int* flag,
                                                   float* zbuf, int nzero) {
    if (blockIdx.x == 0) {
        __shared__ int cnt[256];
        int c = 0;
        for (int i = threadIdx.x; i < 8192; i += 256) {
            int e = (hs[i] >> 7) & 0xFF;
            if (e == 0 || e == 0xFF || e < 96 || e > 159) c++;
        }
        cnt[threadIdx.x] = c;
        __syncthreads();
        for (int s = 128; s > 0; s >>= 1) {
            if (threadIdx.x < s) cnt[threadIdx.x] += cnt[threadIdx.x + s];
            __syncthreads();
        }
        if (threadIdx.x == 0) *flag = (cnt[0] < 512) ? 1 : 0;
    } else {
        int i = (blockIdx.x - 1) * 256 + threadIdx.x;
        if (i < nzero) zbuf[i] = 0.f;
    }
}

// ---------- fused convert; big bf16 segments skipped (read direct) ----------
struct SrcPtrs { const void* p[10]; };

__device__ __constant__ const size_t SEG_OFF[11] = {
    0, 2097152, 6291456, 6299648, 6301696, 6498304,
    6629376, 6631424, 6664192, 6666240, 8763392
};

__global__ __launch_bounds__(256) void convert_all(SrcPtrs s, bf16* __restrict__ dst,
                                                   const int* __restrict__ flag) {
    size_t e = ((size_t)blockIdx.x * 256 + threadIdx.x) * 4;
    if (e >= SEG_OFF[10]) return;
    int seg = 0;
    #pragma unroll
    for (int i = 1; i < 10; ++i) if (e >= SEG_OFF[i]) seg = i;
    int isbf = *flag;
    if (isbf && (seg == 0 || seg == 1 || seg == 9)) return;
    size_t loc = e - SEG_OFF[seg];
    if (isbf) {
        ushort4 v = ((const ushort4*)s.p[seg])[loc / 4];
        ((ushort4*)(dst + e))[0] = v;
    } else {
        float4 v = ((const float4*)s.p[seg])[loc / 4];
        ushort4 o;
        o.x = bf_bits(v.x); o.y = bf_bits(v.y);
        o.z = bf_bits(v.z); o.w = bf_bits(v.w);
        ((ushort4*)(dst + e))[0] = o;
    }
}

// ---------------- MFMA GEMM: C[m][n] = sum_k A[m][k]*B[n][k], bf16 in, 128x128 tile ----
// OUTMODE: 0 = bf16 store; 2 = f32 split-K partials; 3 = f32 atomicAdd col<96;
//          4 = f32 softplus(v + bias[row])
template <int OUTMODE>
__global__ __launch_bounds__(256) void gemm_mfma(
    const bf16* __restrict__ A, int lda,
    const bf16* __restrict__ Bm, int ldb,
    void* __restrict__ C, int ldc,
    int Kspl, size_t pstride,
    const bf16* __restrict__ bias,
    const bf16* __restrict__ Aalt,
    const bf16* __restrict__ Balt,
    const int* __restrict__ flag)
{
    if (flag && *flag) {
        if (Aalt) A = Aalt;
        if (Balt) Bm = Balt;
    }
    __shared__ __align__(16) __bf16 sA[128 * 32];
    __shared__ __align__(16) __bf16 sB[128 * 32];
    const int tid = threadIdx.x;
    const int m0 = blockIdx.y * 128;
    const int n0 = blockIdx.x * 128;
    const int wid = tid >> 6, ln = tid & 63;
    const int wy = (wid >> 1) * 64, wx = (wid & 1) * 64;
    const int q = ln >> 4, m16 = ln & 15;
    const int kbeg = blockIdx.z * Kspl;

    f32x4 acc[4][4] = {};

    for (int k0 = kbeg; k0 < kbeg + Kspl; k0 += 32) {
        #pragma unroll
        for (int i = 0; i < 2; ++i) {
            int idx = tid + i * 256;
            int r = idx >> 2, c = (idx & 3) * 8;
            gload16(&A[(size_t)(m0 + r) * lda + k0 + c], &sA[idx * 8]);
        }
        #pragma unroll
        for (int i = 0; i < 2; ++i) {
            int idx = tid + i * 256;
            int r = idx >> 2, c = (idx & 3) * 8;
            gload16(&Bm[(size_t)(n0 + r) * ldb + k0 + c], &sB[idx * 8]);
        }
        __syncthreads();
        bf16x8 a[4], b[4];
        #pragma unroll
        for (int i = 0; i < 4; ++i)
            a[i] = *(const bf16x8*)&sA[(wy + i * 16 + m16) * 32 + q * 8];
        #pragma unroll
        for (int j = 0; j < 4; ++j)
            b[j] = *(const bf16x8*)&sB[(wx + j * 16 + m16) * 32 + q * 8];
        #pragma unroll
        for (int i = 0; i < 4; ++i)
            #pragma unroll
            for (int j = 0; j < 4; ++j)
                acc[i][j] = __builtin_amdgcn_mfma_f32_16x16x32_bf16(a[i], b[j], acc[i][j], 0, 0, 0);
        __syncthreads();
    }

    #pragma unroll
    for (int i = 0; i < 4; ++i) {
        #pragma unroll
        for (int j = 0; j < 4; ++j) {
            #pragma unroll
            for (int r = 0; r < 4; ++r) {
                int row = m0 + wy + i * 16 + q * 4 + r;
                int col = n0 + wx + j * 16 + m16;
                size_t idx = (size_t)row * ldc + col;
                float v = acc[i][j][r];
                if constexpr (OUTMODE == 0) {
                    ((bf16*)C)[idx] = __float2bfloat16(v);
                } else if constexpr (OUTMODE == 2) {
                    ((float*)C + blockIdx.z * pstride)[idx] = v;
                } else if constexpr (OUTMODE == 3) {
                    if (col < 96) atomicAdd((float*)C + idx, v);
                } else if constexpr (OUTMODE == 4) {
                    ((float*)C)[idx] = softplus_f(v + to_f(bias[row]));
                }
            }
        }
    }
}

// sum the two split-K partials, store to d_out as bf16 or f32 per flag
__global__ __launch_bounds__(256) void sum_store(
    const float* __restrict__ p0, const float* __restrict__ p1,
    void* __restrict__ out, const int* __restrict__ flag, int n4)
{
    int i = blockIdx.x * 256 + threadIdx.x;
    if (i >= n4) return;
    float4 a = ((const float4*)p0)[i];
    float4 b = ((const float4*)p1)[i];
    float4 sv; sv.x = a.x + b.x; sv.y = a.y + b.y; sv.z = a.z + b.z; sv.w = a.w + b.w;
    if (*flag) {
        ushort4 o;
        o.x = bf_bits(sv.x); o.y = bf_bits(sv.y);
        o.z = bf_bits(sv.z); o.w = bf_bits(sv.w);
        ((ushort4*)out)[i] = o;
    } else {
        ((float4*)out)[i] = sv;
    }
}

// ---------------- transpose (d,row) -> (row,d), 64x64 LDS tiles ----------------
__global__ __launch_bounds__(256) void transpose_bf16(
    const ushort* __restrict__ src,   // (DINNER, ROWS)
    ushort* __restrict__ dst)         // (ROWS, DINNER)
{
    __shared__ ushort t[64][65];
    const int bx = blockIdx.x;        // row-tile
    const int by = blockIdx.y;        // d-tile
    const int tid = threadIdx.x;
    const int lr = tid & 63;
    const int ld = tid >> 6;          // 0..3
    #pragma unroll
    for (int i = 0; i < 16; ++i) {
        int d = ld + i * 4;
        t[d][lr] = src[(size_t)(by * 64 + d) * ROWS + bx * 64 + lr];
    }
    __syncthreads();
    #pragma unroll
    for (int i = 0; i < 16; ++i) {
        int r = ld + i * 4;
        dst[(size_t)(bx * 64 + r) * DINNER + by * 64 + lr] = t[lr][r];
    }
}

// ---------------- xd post: xd (2048,96) f32 -> xdT (96,2048) f32 + xd_bf bf16 ----------
__global__ __launch_bounds__(256) void xd_post(
    const float* __restrict__ xd,
    float* __restrict__ xdT,
    bf16* __restrict__ xd_bf)
{
    __shared__ float t[96][65];
    const int row0 = blockIdx.x * 64;
    const int tid = threadIdx.x;
    for (int i = tid; i < 64 * 96; i += 256) {
        int row = i / 96, r = i - row * 96;
        float v = xd[(size_t)(row0 + row) * 96 + r];
        t[r][row] = v;
        xd_bf[(size_t)(row0 + row) * 96 + r] = __float2bfloat16(v);
    }
    __syncthreads();
    for (int i = tid; i < 96 * 64; i += 256) {
        int r = i >> 6, row = i & 63;
        xdT[(size_t)r * ROWS + row0 + row] = t[r][row];
    }
}

// ---------------- conv: 8 outputs per thread along L ----------------
__global__ __launch_bounds__(256) void conv_silu_T8(
    const bf16* __restrict__ xzT,
    const bf16* __restrict__ w,
    const bf16* __restrict__ bias,
    bf16* __restrict__ utT)
{
    int t = blockIdx.x * 256 + threadIdx.x;
    int r0 = (t * 8) & (ROWS - 1);
    int d = t >> 8;

    const ushort* xp = (const ushort*)xzT + (size_t)d * ROWS + r0;
    float x[11];
    us8 cur = *(const us8*)xp;
    #pragma unroll
    for (int j = 0; j < 8; ++j) x[3 + j] = bfu(cur[j]);
    if ((r0 & (SEQLEN - 1)) != 0) {
        ushort4 pv = *(const ushort4*)(xp - 4);
        x[0] = bfu(pv.y); x[1] = bfu(pv.z); x[2] = bfu(pv.w);
    } else {
        x[0] = x[1] = x[2] = 0.f;
    }

    ushort4 wv = *(const ushort4*)((const ushort*)w + d * 4);
    float w0 = bfu(wv.x), w1 = bfu(wv.y), w2 = bfu(wv.z), w3 = bfu(wv.w);
    float bv = to_f(bias[d]);

    us8 o;
    #pragma unroll
    for (int j = 0; j < 8; ++j) {
        float acc = bv;
        acc = fmaf(x[j],     w0, acc);
        acc = fmaf(x[j + 1], w1, acc);
        acc = fmaf(x[j + 2], w2, acc);
        acc = fmaf(x[j + 3], w3, acc);
        o[j] = bf_bits(silu_f(acc));
    }
    *(us8*)((ushort*)utT + (size_t)d * ROWS + r0) = o;
}

// ---------------- scan v13: v12 superposition + 512-thr blocks (4 blocks/CU) ----
// Block = 512 thr = 16 L-chunks x 2 d x 16 n; grid = BATCH * DINNER/2 = 2048.
// 8 waves/block -> 4 resident blocks/CU (wave-limited), so barriers and the
// serial phase-2 fold of one block overlap with 3 other blocks' compute.
// sH/sP packed into float2 (1 ds_read_b64 per fold step); no LDS padding
// (phase-3 reads are 16-lane broadcasts - conflict-free by definition).
#define SCHUNK 16
#define SSTEPS (SEQLEN / SCHUNK)   // 64
__global__ __launch_bounds__(512) void scan_kernel13(
    const float* __restrict__ deltaT,  // (DINNER, ROWS) f32
    const bf16*  __restrict__ utT,     // (DINNER, ROWS)
    const float* __restrict__ xdT,     // (96, ROWS): row 64+n = B_n, 80+n = C_n
    const bf16*  __restrict__ xzT,     // (4096, ROWS): z at row DINNER+d
    const bf16*  __restrict__ A_log,   // (DINNER,16)
    const bf16*  __restrict__ Dp,      // (DINNER,)
    bf16* __restrict__ outzT)          // (DINNER, ROWS)
{
    __shared__ float2 sHP[SCHUNK][32];
    __shared__ float sQ[SCHUNK][2][SSTEPS];
    __shared__ float sS[SCHUNK][2][SSTEPS];
    const int tid = threadIdx.x;
    const int c = tid >> 5;            // chunk 0..15
    const int w = tid & 31;            // (dcol, n)
    const int dcol = (tid >> 4) & 1;
    const int n = tid & 15;
    const int b = blockIdx.x >> 10;
    const int d = ((blockIdx.x & 1023) << 1) + dcol;
    const int row0 = b * SEQLEN + c * SSTEPS;

    const float Aa2 = -expf(to_f(A_log[d * DSTATE + n])) * LOG2E;
    const float Dv = to_f(Dp[d]);

    const float*  dp = deltaT + (size_t)d * ROWS + row0;
    const ushort* up = (const ushort*)utT + (size_t)d * ROWS + row0;
    const ushort* zp = (const ushort*)xzT + (size_t)(DINNER + d) * ROWS + row0;
    const float*  Bp = xdT + (size_t)(64 + n) * ROWS + row0;
    const float*  Cp = xdT + (size_t)(80 + n) * ROWS + row0;

    // ---- phase 1: local scan; produce q_t (lane15) and S_t; prefetched ----
    // NOTE: last-iteration prefetch reads 16B past the logical row; all five
    // streams are interior workspace regions followed by more workspace, so
    // the over-read is in-bounds of d_ws and the values are never used.
    float hl = 0.f, sd = 0.f;
    float4  dv4 = *(const float4*)(dp);
    ushort4 uv4 = *(const ushort4*)(up);
    float4  Bv4 = *(const float4*)(Bp);
    float4  Cv4 = *(const float4*)(Cp);
    for (int i0 = 0; i0 < SSTEPS; i0 += 4) {
        float4  dvn = *(const float4*)(dp + i0 + 4);
        ushort4 uvn = *(const ushort4*)(up + i0 + 4);
        float4  Bvn = *(const float4*)(Bp + i0 + 4);
        float4  Cvn = *(const float4*)(Cp + i0 + 4);
        float dv[4] = {dv4.x, dv4.y, dv4.z, dv4.w};
        float uv[4] = {bfu(uv4.x), bfu(uv4.y), bfu(uv4.z), bfu(uv4.w)};
        float Bv[4] = {Bv4.x, Bv4.y, Bv4.z, Bv4.w};
        float Cv[4] = {Cv4.x, Cv4.y, Cv4.z, Cv4.w};
        float qv[4], sv[4];
        #pragma unroll
        for (int j = 0; j < 4; ++j) {
            sd += dv[j];
            sv[j] = sd;
            float a = fexp2(dv[j] * Aa2);
            hl = fmaf(a, hl, dv[j] * Bv[j] * uv[j]);
            float p = hl * Cv[j];
            p = row16_sum_to_lane15(p);
            qv[j] = fmaf(uv[j], Dv, p);
        }
        if (n == 15) {
            float4 qo; qo.x = qv[0]; qo.y = qv[1]; qo.z = qv[2]; qo.w = qv[3];
            float4 so; so.x = sv[0]; so.y = sv[1]; so.z = sv[2]; so.w = sv[3];
            *(float4*)&sQ[c][dcol][i0] = qo;
            *(float4*)&sS[c][dcol][i0] = so;
        }
        dv4 = dvn; uv4 = uvn; Bv4 = Bvn; Cv4 = Cvn;
    }
    sHP[c][w] = make_float2(hl, fexp2(sd * Aa2));
    __syncthreads();

    // ---- phase 2: fold preceding chunk summaries (1 b64 read / step) ----
    float hin = 0.f;
    for (int cc = 0; cc < c; ++cc) {
        float2 hp = sHP[cc][w];
        hin = fmaf(hp.y, hin, hp.x);
    }

    // ---- phase 3: chain-free correction; 2 light streams, prefetched ----
    ushort4 zv4 = *(const ushort4*)(zp);
    float4  Cw4 = *(const float4*)(Cp);
    for (int i0 = 0; i0 < SSTEPS; i0 += 4) {
        ushort4 zvn = *(const ushort4*)(zp + i0 + 4);
        float4  Cwn = *(const float4*)(Cp + i0 + 4);
        float4 q4 = *(const float4*)&sQ[c][dcol][i0];
        float4 s4 = *(const float4*)&sS[c][dcol][i0];
        float Cv[4] = {Cw4.x, Cw4.y, Cw4.z, Cw4.w};
        float ss[4] = {s4.x, s4.y, s4.z, s4.w};
        float qq[4] = {q4.x, q4.y, q4.z, q4.w};
        float zv[4] = {bfu(zv4.x), bfu(zv4.y), bfu(zv4.z), bfu(zv4.w)};
        float y[4];
        #pragma unroll
        for (int j = 0; j < 4; ++j) {
            float e = fexp2(ss[j] * Aa2);
            float p = (hin * e) * Cv[j];
            p = row16_sum_to_lane15(p);
            y[j] = qq[j] + p;
        }
        if (n == 15) {
            ushort4 o;
            o.x = bf_bits(y[0] * silu_f(zv[0]));
            o.y = bf_bits(y[1] * silu_f(zv[1]));
            o.z = bf_bits(y[2] * silu_f(zv[2]));
            o.w = bf_bits(y[3] * silu_f(zv[3]));
            *(ushort4*)((ushort*)outzT + (size_t)d * ROWS + row0 + i0) = o;
        }
        zv4 = zvn; Cw4 = Cwn;
    }
}

extern "C" void kernel_launch(void* const* d_in, const int* in_sizes, int n_in,
                              void* d_out, int out_size, void* d_ws, size_t ws_size,
                              hipStream_t stream) {
    static const size_t SZ[10] = {
        (size_t)BATCH * SEQLEN * DMODEL,        // hidden_states
        (size_t)2 * DINNER * DMODEL,            // in_proj_w
        (size_t)DINNER * 4,                     // conv1d_w
        (size_t)DINNER,                         // conv1d_b
        (size_t)(DTRANK + 2 * DSTATE) * DINNER, // x_proj_w
        (size_t)DINNER * DTRANK,                // dt_proj_w
        (size_t)DINNER,                         // dt_proj_b
        (size_t)DINNER * DSTATE,                // A_log
        (size_t)DINNER,                         // D_param
        (size_t)DMODEL * DINNER                 // out_proj_w
    };
    size_t tot_in = 0;
    for (int i = 0; i < 10; ++i) tot_in += SZ[i];

    char* p = (char*)d_ws;
    int* flag = (int*)p;                     p += 64;
    bf16* inb = (bf16*)p;                    p += tot_in * 2;
    bf16* xzT = (bf16*)p;                    p += (size_t)4096 * ROWS * 2;
    bf16* utT = (bf16*)p;                    p += (size_t)DINNER * ROWS * 2;
    bf16* ut  = (bf16*)p;                    p += (size_t)ROWS * DINNER * 2;
    float* xd = (float*)p;                   p += (size_t)ROWS * 96 * 4;
    bf16* xd_bf = (bf16*)p;                  p += (size_t)ROWS * 96 * 2;
    float* xdT = (float*)p;                  p += (size_t)96 * ROWS * 4;
    float* deltaT = (float*)p;               p += (size_t)DINNER * ROWS * 4;
    bf16* outzT = (bf16*)p;                  p += (size_t)DINNER * ROWS * 2;
    bf16* outz = (bf16*)p;                   p += (size_t)ROWS * DINNER * 2;
    float* part = (float*)p;                 p += (size_t)2 * ROWS * DMODEL * 4;
    size_t needed = (size_t)(p - (char*)d_ws);
    if (ws_size < needed) return;

    dim3 blk(256);

    // 0) detect dtype + zero xd (for atomic accumulation)
    prep_kernel<<<1 + (ROWS * 96 + 255) / 256, blk, 0, stream>>>(
        (const unsigned short*)d_in[0], flag, xd, ROWS * 96);

    bf16* inp[10];
    {
        size_t off = 0;
        for (int i = 0; i < 10; ++i) { inp[i] = inb + off; off += SZ[i]; }
    }
    SrcPtrs sp;
    for (int i = 0; i < 10; ++i) sp.p[i] = d_in[i];
    convert_all<<<(int)((tot_in / 4 + 255) / 256), blk, 0, stream>>>(sp, inb, flag);

    const bf16* hs        = inp[0];
    const bf16* in_proj_w = inp[1];
    const bf16* conv_w    = inp[2];
    const bf16* conv_b    = inp[3];
    const bf16* x_proj_w  = inp[4];
    const bf16* dt_proj_w = inp[5];
    const bf16* dt_proj_b = inp[6];
    const bf16* A_log     = inp[7];
    const bf16* Dp        = inp[8];
    const bf16* out_proj_w= inp[9];

    // 1) xzT = (hs @ in_proj_w^T)^T : dual-ptr — reads d_in directly when bf16
    gemm_mfma<0><<<dim3(ROWS / 128, 4096 / 128, 1), blk, 0, stream>>>(
        in_proj_w, DMODEL, hs, DMODEL, xzT, ROWS, DMODEL, 0, nullptr,
        (const bf16*)d_in[1], (const bf16*)d_in[0], flag);

    // 2) utT = silu(causal depthwise conv along L), d-major
    conv_silu_T8<<<(DINNER * ROWS / 8) / 256, blk, 0, stream>>>(xzT, conv_w, conv_b, utT);

    // 2b) ut = utT^T (row-major, for MFMA x_proj)
    transpose_bf16<<<dim3(ROWS / 64, DINNER / 64), blk, 0, stream>>>(
        (const ushort*)utT, (ushort*)ut);

    // 3) xd[row][r] = sum_d ut[row][d] * x_proj_w[r][d]  (MFMA, split-K=4, atomic f32)
    gemm_mfma<3><<<dim3(1, ROWS / 128, 4), blk, 0, stream>>>(
        ut, DINNER, x_proj_w, DINNER, xd, 96, DINNER / 4, 0, nullptr,
        nullptr, nullptr, nullptr);

    // 3b) xdT = xd^T (f32, scan layout) + xd_bf (bf16 row-major, dt GEMM operand)
    xd_post<<<ROWS / 64, blk, 0, stream>>>(xd, xdT, xd_bf);

    // 4) deltaT[d][row] = softplus(sum_r dtw[d][r]*xd[row][r] + dtb[d])  (MFMA K=64)
    gemm_mfma<4><<<dim3(ROWS / 128, DINNER / 128, 1), blk, 0, stream>>>(
        dt_proj_w, DTRANK, xd_bf, 96, deltaT, ROWS, DTRANK, 0, dt_proj_b,
        nullptr, nullptr, nullptr);

    // 5) chunk-parallel selective scan -> outzT (d-major, full-line writes)
    scan_kernel13<<<BATCH * (DINNER / 2), dim3(512), 0, stream>>>(
        deltaT, utT, xdT, xzT, A_log, Dp, outzT);

    // 5b) outz = outzT^T (row-major for gemm6)
    transpose_bf16<<<dim3(ROWS / 64, DINNER / 64), blk, 0, stream>>>(
        (const ushort*)outzT, (ushort*)outz);

    // 6) out = outz @ out_proj_w^T  (MFMA split-K=2 -> f32 partials; dual-ptr B)
    gemm_mfma<2><<<dim3(DMODEL / 128, ROWS / 128, 2), blk, 0, stream>>>(
        outz, DINNER, out_proj_w, DINNER, part, DMODEL, DINNER / 2, (size_t)ROWS * DMODEL,
        nullptr, nullptr, (const bf16*)d_in[9], flag);

    // 6b) out = cvt(part0 + part1)
    sum_store<<<(ROWS * DMODEL / 4 + 255) / 256, blk, 0, stream>>>(
        part, part + (size_t)ROWS * DMODEL, d_out, flag, ROWS * DMODEL / 4);
}

// Round 4
// 333.976 us; speedup vs baseline: 1.1152x; 1.1152x over previous
//
#include <hip/hip_runtime.h>
#include <hip/hip_bf16.h>

// Shapes: B=2, L=1024, D_MODEL=1024, D_INNER=2048, D_STATE=16, D_CONV=4, DT_RANK=64
#define BATCH 2
#define SEQLEN 1024
#define DMODEL 1024
#define DINNER 2048
#define DSTATE 16
#define DTRANK 64
#define ROWS (BATCH * SEQLEN) // 2048
#define LOG2E 1.44269504088896340736f

using bf16 = __hip_bfloat16;
typedef __bf16 bf16x8 __attribute__((ext_vector_type(8)));
typedef float f32x4 __attribute__((ext_vector_type(4)));
typedef unsigned short us8 __attribute__((ext_vector_type(8)));

__device__ __forceinline__ float to_f(float x) { return x; }
__device__ __forceinline__ float to_f(bf16 x) { return __bfloat162float(x); }

__device__ __forceinline__ float fexp2(float x) { return __builtin_amdgcn_exp2f(x); }

__device__ __forceinline__ float bfu(unsigned short u) {
    union { unsigned int i; float f; } v;
    v.i = ((unsigned int)u) << 16;
    return v.f;
}

__device__ __forceinline__ unsigned short bf_bits(float x) {
    bf16 h = __float2bfloat16(x);
    union { bf16 b; unsigned short u; } cv;
    cv.b = h;
    return cv.u;
}

__device__ __forceinline__ float softplus_f(float x) {
    return fmaxf(x, 0.f) + log1pf(expf(-fabsf(x)));
}
// fast silu
__device__ __forceinline__ float silu_f(float x) {
    return x * __builtin_amdgcn_rcpf(1.f + fexp2(-x * LOG2E));
}

// DPP row_shr move (within 16-lane row); invalid source lanes contribute 0.
template <int CTRL>
__device__ __forceinline__ float dpp_shr(float x) {
    int r = __builtin_amdgcn_update_dpp(0, __builtin_bit_cast(int, x), CTRL, 0xF, 0xF, false);
    return __builtin_bit_cast(float, r);
}
// 16-lane reduce: lane (n==15) of each row16 holds the sum.
__device__ __forceinline__ float row16_sum_to_lane15(float p) {
    p += dpp_shr<0x111>(p);  // row_shr:1
    p += dpp_shr<0x112>(p);  // row_shr:2
    p += dpp_shr<0x114>(p);  // row_shr:4
    p += dpp_shr<0x118>(p);  // row_shr:8
    return p;
}

// async 16B global -> LDS
__device__ __forceinline__ void gload16(const void* g, void* l) {
    __builtin_amdgcn_global_load_lds(
        (const __attribute__((address_space(1))) void*)g,
        (__attribute__((address_space(3))) void*)l, 16, 0, 0);
}

// ---------- prep: block 0 = dtype detect; blocks 1.. zero xd ----------
__global__ __launch_bounds__(256) void prep_kernel(const unsigned short* hs, int* flag,
                                                   float* zbuf, int nzero) {
    if (blockIdx.x == 0) {
        __shared__ int cnt[256];
        int c = 0;
        for (int i = threadIdx.x; i < 8192; i += 256) {
            int e = (hs[i] >> 7) & 0xFF;
            if (e == 0 || e == 0xFF || e < 96 || e > 159) c++;
        }
        cnt[threadIdx.x] = c;
        __syncthreads();
        for (int s = 128; s > 0; s >>= 1) {
            if (threadIdx.x < s) cnt[threadIdx.x] += cnt[threadIdx.x + s];
            __syncthreads();
        }
        if (threadIdx.x == 0) *flag = (cnt[0] < 512) ? 1 : 0;
    } else {
        int i = (blockIdx.x - 1) * 256 + threadIdx.x;
        if (i < nzero) zbuf[i] = 0.f;
    }
}

// ---------- fused convert; big bf16 segments skipped (read direct) ----------
struct SrcPtrs { const void* p[10]; };

__device__ __constant__ const size_t SEG_OFF[11] = {
    0, 2097152, 6291456, 6299648, 6301696, 6498304,
    6629376, 6631424, 6664192, 6666240, 8763392
};

__global__ __launch_bounds__(256) void convert_all(SrcPtrs s, bf16* __restrict__ dst,
                                                   const int* __restrict__ flag) {
    size_t e = ((size_t)blockIdx.x * 256 + threadIdx.x) * 4;
    if (e >= SEG_OFF[10]) return;
    int seg = 0;
    #pragma unroll
    for (int i = 1; i < 10; ++i) if (e >= SEG_OFF[i]) seg = i;
    int isbf = *flag;
    if (isbf && (seg == 0 || seg == 1 || seg == 9)) return;
    size_t loc = e - SEG_OFF[seg];
    if (isbf) {
        ushort4 v = ((const ushort4*)s.p[seg])[loc / 4];
        ((ushort4*)(dst + e))[0] = v;
    } else {
        float4 v = ((const float4*)s.p[seg])[loc / 4];
        ushort4 o;
        o.x = bf_bits(v.x); o.y = bf_bits(v.y);
        o.z = bf_bits(v.z); o.w = bf_bits(v.w);
        ((ushort4*)(dst + e))[0] = o;
    }
}

// ---------------- MFMA GEMM: C[m][n] = sum_k A[m][k]*B[n][k], bf16 in, 128x128 tile ----
// OUTMODE: 0 = bf16 store; 2 = f32 split-K partials; 3 = f32 atomicAdd col<96;
//          4 = f32 softplus(v + bias[row])
template <int OUTMODE>
__global__ __launch_bounds__(256) void gemm_mfma(
    const bf16* __restrict__ A, int lda,
    const bf16* __restrict__ Bm, int ldb,
    void* __restrict__ C, int ldc,
    int Kspl, size_t pstride,
    const bf16* __restrict__ bias,
    const bf16* __restrict__ Aalt,
    const bf16* __restrict__ Balt,
    const int* __restrict__ flag)
{
    if (flag && *flag) {
        if (Aalt) A = Aalt;
        if (Balt) Bm = Balt;
    }
    __shared__ __align__(16) __bf16 sA[128 * 32];
    __shared__ __align__(16) __bf16 sB[128 * 32];
    const int tid = threadIdx.x;
    const int m0 = blockIdx.y * 128;
    const int n0 = blockIdx.x * 128;
    const int wid = tid >> 6, ln = tid & 63;
    const int wy = (wid >> 1) * 64, wx = (wid & 1) * 64;
    const int q = ln >> 4, m16 = ln & 15;
    const int kbeg = blockIdx.z * Kspl;

    f32x4 acc[4][4] = {};

    for (int k0 = kbeg; k0 < kbeg + Kspl; k0 += 32) {
        #pragma unroll
        for (int i = 0; i < 2; ++i) {
            int idx = tid + i * 256;
            int r = idx >> 2, c = (idx & 3) * 8;
            gload16(&A[(size_t)(m0 + r) * lda + k0 + c], &sA[idx * 8]);
        }
        #pragma unroll
        for (int i = 0; i < 2; ++i) {
            int idx = tid + i * 256;
            int r = idx >> 2, c = (idx & 3) * 8;
            gload16(&Bm[(size_t)(n0 + r) * ldb + k0 + c], &sB[idx * 8]);
        }
        __syncthreads();
        bf16x8 a[4], b[4];
        #pragma unroll
        for (int i = 0; i < 4; ++i)
            a[i] = *(const bf16x8*)&sA[(wy + i * 16 + m16) * 32 + q * 8];
        #pragma unroll
        for (int j = 0; j < 4; ++j)
            b[j] = *(const bf16x8*)&sB[(wx + j * 16 + m16) * 32 + q * 8];
        #pragma unroll
        for (int i = 0; i < 4; ++i)
            #pragma unroll
            for (int j = 0; j < 4; ++j)
                acc[i][j] = __builtin_amdgcn_mfma_f32_16x16x32_bf16(a[i], b[j], acc[i][j], 0, 0, 0);
        __syncthreads();
    }

    #pragma unroll
    for (int i = 0; i < 4; ++i) {
        #pragma unroll
        for (int j = 0; j < 4; ++j) {
            #pragma unroll
            for (int r = 0; r < 4; ++r) {
                int row = m0 + wy + i * 16 + q * 4 + r;
                int col = n0 + wx + j * 16 + m16;
                size_t idx = (size_t)row * ldc + col;
                float v = acc[i][j][r];
                if constexpr (OUTMODE == 0) {
                    ((bf16*)C)[idx] = __float2bfloat16(v);
                } else if constexpr (OUTMODE == 2) {
                    ((float*)C + blockIdx.z * pstride)[idx] = v;
                } else if constexpr (OUTMODE == 3) {
                    if (col < 96) atomicAdd((float*)C + idx, v);
                } else if constexpr (OUTMODE == 4) {
                    ((float*)C)[idx] = softplus_f(v + to_f(bias[row]));
                }
            }
        }
    }
}

// sum the two split-K partials, store to d_out as bf16 or f32 per flag
__global__ __launch_bounds__(256) void sum_store(
    const float* __restrict__ p0, const float* __restrict__ p1,
    void* __restrict__ out, const int* __restrict__ flag, int n4)
{
    int i = blockIdx.x * 256 + threadIdx.x;
    if (i >= n4) return;
    float4 a = ((const float4*)p0)[i];
    float4 b = ((const float4*)p1)[i];
    float4 sv; sv.x = a.x + b.x; sv.y = a.y + b.y; sv.z = a.z + b.z; sv.w = a.w + b.w;
    if (*flag) {
        ushort4 o;
        o.x = bf_bits(sv.x); o.y = bf_bits(sv.y);
        o.z = bf_bits(sv.z); o.w = bf_bits(sv.w);
        ((ushort4*)out)[i] = o;
    } else {
        ((float4*)out)[i] = sv;
    }
}

// ---------------- transpose (d,row) -> (row,d), 64x64 LDS tiles ----------------
__global__ __launch_bounds__(256) void transpose_bf16(
    const ushort* __restrict__ src,   // (DINNER, ROWS)
    ushort* __restrict__ dst)         // (ROWS, DINNER)
{
    __shared__ ushort t[64][65];
    const int bx = blockIdx.x;        // row-tile
    const int by = blockIdx.y;        // d-tile
    const int tid = threadIdx.x;
    const int lr = tid & 63;
    const int ld = tid >> 6;          // 0..3
    #pragma unroll
    for (int i = 0; i < 16; ++i) {
        int d = ld + i * 4;
        t[d][lr] = src[(size_t)(by * 64 + d) * ROWS + bx * 64 + lr];
    }
    __syncthreads();
    #pragma unroll
    for (int i = 0; i < 16; ++i) {
        int r = ld + i * 4;
        dst[(size_t)(bx * 64 + r) * DINNER + by * 64 + lr] = t[lr][r];
    }
}

// ---------------- xd cvt: xd (2048,96) f32 -> xd_bf bf16 (row-major) ----------------
__global__ __launch_bounds__(256) void xd_cvt(
    const float* __restrict__ xd,
    bf16* __restrict__ xd_bf)
{
    int i = blockIdx.x * 256 + threadIdx.x;   // float4 index; grid sized exactly
    float4 v = ((const float4*)xd)[i];
    ushort4 o;
    o.x = bf_bits(v.x); o.y = bf_bits(v.y);
    o.z = bf_bits(v.z); o.w = bf_bits(v.w);
    ((ushort4*)xd_bf)[i] = o;
}

// ---------------- conv: 8 outputs per thread along L ----------------
__global__ __launch_bounds__(256) void conv_silu_T8(
    const bf16* __restrict__ xzT,
    const bf16* __restrict__ w,
    const bf16* __restrict__ bias,
    bf16* __restrict__ utT)
{
    int t = blockIdx.x * 256 + threadIdx.x;
    int r0 = (t * 8) & (ROWS - 1);
    int d = t >> 8;

    const ushort* xp = (const ushort*)xzT + (size_t)d * ROWS + r0;
    float x[11];
    us8 cur = *(const us8*)xp;
    #pragma unroll
    for (int j = 0; j < 8; ++j) x[3 + j] = bfu(cur[j]);
    if ((r0 & (SEQLEN - 1)) != 0) {
        ushort4 pv = *(const ushort4*)(xp - 4);
        x[0] = bfu(pv.y); x[1] = bfu(pv.z); x[2] = bfu(pv.w);
    } else {
        x[0] = x[1] = x[2] = 0.f;
    }

    ushort4 wv = *(const ushort4*)((const ushort*)w + d * 4);
    float w0 = bfu(wv.x), w1 = bfu(wv.y), w2 = bfu(wv.z), w3 = bfu(wv.w);
    float bv = to_f(bias[d]);

    us8 o;
    #pragma unroll
    for (int j = 0; j < 8; ++j) {
        float acc = bv;
        acc = fmaf(x[j],     w0, acc);
        acc = fmaf(x[j + 1], w1, acc);
        acc = fmaf(x[j + 2], w2, acc);
        acc = fmaf(x[j + 3], w3, acc);
        o[j] = bf_bits(silu_f(acc));
    }
    *(us8*)((ushort*)utT + (size_t)d * ROWS + r0) = o;
}

// ---------------- scan v14: v12 superposition + coalesced row-major B/C loads ----
// Block = 1024 thr = 16 L-chunks(waves) x 4 d x 16 n; grid = BATCH * DINNER/4.
// B/C now read from the row-major xd buffer (row, 96): B at col 64+n, C at 80+n.
// Lane n's scalar load -> 16 lanes read 64 CONSECUTIVE bytes (1-2 cache lines,
// dcol groups broadcast), replacing the old n-major float4 gathers that touched
// 16 distinct lines 8KB apart per instruction. 8 scalar dwords/iter, prefetched.
#define SCHUNK 16
#define SSTEPS (SEQLEN / SCHUNK)   // 64
__global__ __launch_bounds__(1024) void scan_kernel14(
    const float* __restrict__ deltaT,  // (DINNER, ROWS) f32
    const bf16*  __restrict__ utT,     // (DINNER, ROWS)
    const float* __restrict__ xd96,    // (ROWS, 96) f32: col 64+n = B_n, 80+n = C_n
    const bf16*  __restrict__ xzT,     // (4096, ROWS): z at row DINNER+d
    const bf16*  __restrict__ A_log,   // (DINNER,16)
    const bf16*  __restrict__ Dp,      // (DINNER,)
    bf16* __restrict__ outzT)          // (DINNER, ROWS)
{
    __shared__ float2 sHP[SCHUNK][64];
    __shared__ float sQ[SCHUNK][4][68];   // 68 = 64 + 4 pad (bank spread)
    __shared__ float sS[SCHUNK][4][68];
    const int tid = threadIdx.x;
    const int c = tid >> 6;            // wave-uniform chunk id
    const int w = tid & 63;
    const int dcol = (tid >> 4) & 3;
    const int n = tid & 15;
    const int b = blockIdx.x >> 9;
    const int d = ((blockIdx.x & 511) << 2) + dcol;
    const int row0 = b * SEQLEN + c * SSTEPS;

    const float Aa2 = -expf(to_f(A_log[d * DSTATE + n])) * LOG2E;
    const float Dv = to_f(Dp[d]);

    const float*  dp = deltaT + (size_t)d * ROWS + row0;
    const ushort* up = (const ushort*)utT + (size_t)d * ROWS + row0;
    const ushort* zp = (const ushort*)xzT + (size_t)(DINNER + d) * ROWS + row0;
    const float*  bcp = xd96 + (size_t)row0 * 96 + 64 + n;  // B at [t*96], C at [t*96+16]

    // ---- phase 1: local scan; produce q_t (lane15) and S_t; prefetched ----
    // NOTE: last-iteration prefetch reads past the logical chunk; all streams
    // are interior workspace regions followed by more workspace, so the
    // over-read stays inside d_ws and the values are never used.
    float hl = 0.f, sd = 0.f;
    float4  dv4 = *(const float4*)(dp);
    ushort4 uv4 = *(const ushort4*)(up);
    float Bn[4], Cn[4];
    #pragma unroll
    for (int j = 0; j < 4; ++j) {
        Bn[j] = bcp[(size_t)j * 96];
        Cn[j] = bcp[(size_t)j * 96 + 16];
    }
    for (int i0 = 0; i0 < SSTEPS; i0 += 4) {
        float4  dvn = *(const float4*)(dp + i0 + 4);
        ushort4 uvn = *(const ushort4*)(up + i0 + 4);
        float Bpre[4], Cpre[4];
        #pragma unroll
        for (int j = 0; j < 4; ++j) {
            Bpre[j] = bcp[(size_t)(i0 + 4 + j) * 96];
            Cpre[j] = bcp[(size_t)(i0 + 4 + j) * 96 + 16];
        }
        float dv[4] = {dv4.x, dv4.y, dv4.z, dv4.w};
        float uv[4] = {bfu(uv4.x), bfu(uv4.y), bfu(uv4.z), bfu(uv4.w)};
        float qv[4], sv[4];
        #pragma unroll
        for (int j = 0; j < 4; ++j) {
            sd += dv[j];
            sv[j] = sd;
            float a = fexp2(dv[j] * Aa2);
            hl = fmaf(a, hl, dv[j] * Bn[j] * uv[j]);
            float p = hl * Cn[j];
            p = row16_sum_to_lane15(p);
            qv[j] = fmaf(uv[j], Dv, p);
        }
        if (n == 15) {
            float4 qo; qo.x = qv[0]; qo.y = qv[1]; qo.z = qv[2]; qo.w = qv[3];
            float4 so; so.x = sv[0]; so.y = sv[1]; so.z = sv[2]; so.w = sv[3];
            *(float4*)&sQ[c][dcol][i0] = qo;
            *(float4*)&sS[c][dcol][i0] = so;
        }
        dv4 = dvn; uv4 = uvn;
        #pragma unroll
        for (int j = 0; j < 4; ++j) { Bn[j] = Bpre[j]; Cn[j] = Cpre[j]; }
    }
    sHP[c][w] = make_float2(hl, fexp2(sd * Aa2));
    __syncthreads();

    // ---- phase 2: fold preceding chunk summaries (1 b64 read / step) ----
    float hin = 0.f;
    for (int cc = 0; cc < c; ++cc) {
        float2 hp = sHP[cc][w];
        hin = fmaf(hp.y, hin, hp.x);
    }

    // ---- phase 3: chain-free correction; light streams, prefetched ----
    ushort4 zv4 = *(const ushort4*)(zp);
    #pragma unroll
    for (int j = 0; j < 4; ++j) Cn[j] = bcp[(size_t)j * 96 + 16];
    for (int i0 = 0; i0 < SSTEPS; i0 += 4) {
        ushort4 zvn = *(const ushort4*)(zp + i0 + 4);
        float Cpre[4];
        #pragma unroll
        for (int j = 0; j < 4; ++j)
            Cpre[j] = bcp[(size_t)(i0 + 4 + j) * 96 + 16];
        float4 q4 = *(const float4*)&sQ[c][dcol][i0];
        float4 s4 = *(const float4*)&sS[c][dcol][i0];
        float ss[4] = {s4.x, s4.y, s4.z, s4.w};
        float qq[4] = {q4.x, q4.y, q4.z, q4.w};
        float zv[4] = {bfu(zv4.x), bfu(zv4.y), bfu(zv4.z), bfu(zv4.w)};
        float y[4];
        #pragma unroll
        for (int j = 0; j < 4; ++j) {
            float e = fexp2(ss[j] * Aa2);
            float p = (hin * e) * Cn[j];
            p = row16_sum_to_lane15(p);
            y[j] = qq[j] + p;
        }
        if (n == 15) {
            ushort4 o;
            o.x = bf_bits(y[0] * silu_f(zv[0]));
            o.y = bf_bits(y[1] * silu_f(zv[1]));
            o.z = bf_bits(y[2] * silu_f(zv[2]));
            o.w = bf_bits(y[3] * silu_f(zv[3]));
            *(ushort4*)((ushort*)outzT + (size_t)d * ROWS + row0 + i0) = o;
        }
        zv4 = zvn;
        #pragma unroll
        for (int j = 0; j < 4; ++j) Cn[j] = Cpre[j];
    }
}

extern "C" void kernel_launch(void* const* d_in, const int* in_sizes, int n_in,
                              void* d_out, int out_size, void* d_ws, size_t ws_size,
                              hipStream_t stream) {
    static const size_t SZ[10] = {
        (size_t)BATCH * SEQLEN * DMODEL,        // hidden_states
        (size_t)2 * DINNER * DMODEL,            // in_proj_w
        (size_t)DINNER * 4,                     // conv1d_w
        (size_t)DINNER,                         // conv1d_b
        (size_t)(DTRANK + 2 * DSTATE) * DINNER, // x_proj_w
        (size_t)DINNER * DTRANK,                // dt_proj_w
        (size_t)DINNER,                         // dt_proj_b
        (size_t)DINNER * DSTATE,                // A_log
        (size_t)DINNER,                         // D_param
        (size_t)DMODEL * DINNER                 // out_proj_w
    };
    size_t tot_in = 0;
    for (int i = 0; i < 10; ++i) tot_in += SZ[i];

    char* p = (char*)d_ws;
    int* flag = (int*)p;                     p += 64;
    bf16* inb = (bf16*)p;                    p += tot_in * 2;
    bf16* xzT = (bf16*)p;                    p += (size_t)4096 * ROWS * 2;
    bf16* utT = (bf16*)p;                    p += (size_t)DINNER * ROWS * 2;
    bf16* ut  = (bf16*)p;                    p += (size_t)ROWS * DINNER * 2;
    float* xd = (float*)p;                   p += (size_t)ROWS * 96 * 4;
    bf16* xd_bf = (bf16*)p;                  p += (size_t)ROWS * 96 * 2;
    float* deltaT = (float*)p;               p += (size_t)DINNER * ROWS * 4;
    bf16* outzT = (bf16*)p;                  p += (size_t)DINNER * ROWS * 2;
    bf16* outz = (bf16*)p;                   p += (size_t)ROWS * DINNER * 2;
    float* part = (float*)p;                 p += (size_t)2 * ROWS * DMODEL * 4;
    size_t needed = (size_t)(p - (char*)d_ws);
    if (ws_size < needed) return;

    dim3 blk(256);

    // 0) detect dtype + zero xd (for atomic accumulation)
    prep_kernel<<<1 + (ROWS * 96 + 255) / 256, blk, 0, stream>>>(
        (const unsigned short*)d_in[0], flag, xd, ROWS * 96);

    bf16* inp[10];
    {
        size_t off = 0;
        for (int i = 0; i < 10; ++i) { inp[i] = inb + off; off += SZ[i]; }
    }
    SrcPtrs sp;
    for (int i = 0; i < 10; ++i) sp.p[i] = d_in[i];
    convert_all<<<(int)((tot_in / 4 + 255) / 256), blk, 0, stream>>>(sp, inb, flag);

    const bf16* hs        = inp[0];
    const bf16* in_proj_w = inp[1];
    const bf16* conv_w    = inp[2];
    const bf16* conv_b    = inp[3];
    const bf16* x_proj_w  = inp[4];
    const bf16* dt_proj_w = inp[5];
    const bf16* dt_proj_b = inp[6];
    const bf16* A_log     = inp[7];
    const bf16* Dp        = inp[8];
    const bf16* out_proj_w= inp[9];

    // 1) xzT = (hs @ in_proj_w^T)^T : dual-ptr — reads d_in directly when bf16
    gemm_mfma<0><<<dim3(ROWS / 128, 4096 / 128, 1), blk, 0, stream>>>(
        in_proj_w, DMODEL, hs, DMODEL, xzT, ROWS, DMODEL, 0, nullptr,
        (const bf16*)d_in[1], (const bf16*)d_in[0], flag);

    // 2) utT = silu(causal depthwise conv along L), d-major
    conv_silu_T8<<<(DINNER * ROWS / 8) / 256, blk, 0, stream>>>(xzT, conv_w, conv_b, utT);

    // 2b) ut = utT^T (row-major, for MFMA x_proj)
    transpose_bf16<<<dim3(ROWS / 64, DINNER / 64), blk, 0, stream>>>(
        (const ushort*)utT, (ushort*)ut);

    // 3) xd[row][r] = sum_d ut[row][d] * x_proj_w[r][d]  (MFMA, split-K=4, atomic f32)
    gemm_mfma<3><<<dim3(1, ROWS / 128, 4), blk, 0, stream>>>(
        ut, DINNER, x_proj_w, DINNER, xd, 96, DINNER / 4, 0, nullptr,
        nullptr, nullptr, nullptr);

    // 3b) xd_bf = bf16(xd)  (row-major, dt GEMM operand); scan reads xd directly
    xd_cvt<<<ROWS * 96 / 4 / 256, blk, 0, stream>>>(xd, xd_bf);

    // 4) deltaT[d][row] = softplus(sum_r dtw[d][r]*xd[row][r] + dtb[d])  (MFMA K=64)
    gemm_mfma<4><<<dim3(ROWS / 128, DINNER / 128, 1), blk, 0, stream>>>(
        dt_proj_w, DTRANK, xd_bf, 96, deltaT, ROWS, DTRANK, 0, dt_proj_b,
        nullptr, nullptr, nullptr);

    // 5) chunk-parallel selective scan -> outzT (d-major, full-line writes)
    scan_kernel14<<<BATCH * (DINNER / 4), dim3(1024), 0, stream>>>(
        deltaT, utT, xd, xzT, A_log, Dp, outzT);

    // 5b) outz = outzT^T (row-major for gemm6)
    transpose_bf16<<<dim3(ROWS / 64, DINNER / 64), blk, 0, stream>>>(
        (const ushort*)outzT, (ushort*)outz);

    // 6) out = outz @ out_proj_w^T  (MFMA split-K=2 -> f32 partials; dual-ptr B)
    gemm_mfma<2><<<dim3(DMODEL / 128, ROWS / 128, 2), blk, 0, stream>>>(
        outz, DINNER, out_proj_w, DINNER, part, DMODEL, DINNER / 2, (size_t)ROWS * DMODEL,
        nullptr, nullptr, (const bf16*)d_in[9], flag);

    // 6b) out = cvt(part0 + part1)
    sum_store<<<(ROWS * DMODEL / 4 + 255) / 256, blk, 0, stream>>>(
        part, part + (size_t)ROWS * DMODEL, d_out, flag, ROWS * DMODEL / 4);
}

// Round 5
// 300.942 us; speedup vs baseline: 1.2376x; 1.1098x over previous
//
#include <hip/hip_runtime.h>
#include <hip/hip_bf16.h>

// Shapes: B=2, L=1024, D_MODEL=1024, D_INNER=2048, D_STATE=16, D_CONV=4, DT_RANK=64
#define BATCH 2
#define SEQLEN 1024
#define DMODEL 1024
#define DINNER 2048
#define DSTATE 16
#define DTRANK 64
#define ROWS (BATCH * SEQLEN) // 2048
#define LOG2E 1.44269504088896340736f

using bf16 = __hip_bfloat16;
typedef __bf16 bf16x8 __attribute__((ext_vector_type(8)));
typedef float f32x4 __attribute__((ext_vector_type(4)));
typedef unsigned short us8 __attribute__((ext_vector_type(8)));

__device__ __forceinline__ float to_f(float x) { return x; }
__device__ __forceinline__ float to_f(bf16 x) { return __bfloat162float(x); }

__device__ __forceinline__ float fexp2(float x) { return __builtin_amdgcn_exp2f(x); }

__device__ __forceinline__ float bfu(unsigned short u) {
    union { unsigned int i; float f; } v;
    v.i = ((unsigned int)u) << 16;
    return v.f;
}

__device__ __forceinline__ unsigned short bf_bits(float x) {
    bf16 h = __float2bfloat16(x);
    union { bf16 b; unsigned short u; } cv;
    cv.b = h;
    return cv.u;
}

__device__ __forceinline__ float softplus_f(float x) {
    return fmaxf(x, 0.f) + log1pf(expf(-fabsf(x)));
}
// fast silu
__device__ __forceinline__ float silu_f(float x) {
    return x * __builtin_amdgcn_rcpf(1.f + fexp2(-x * LOG2E));
}

// DPP row_shr move (within 16-lane row); invalid source lanes contribute 0.
template <int CTRL>
__device__ __forceinline__ float dpp_shr(float x) {
    int r = __builtin_amdgcn_update_dpp(0, __builtin_bit_cast(int, x), CTRL, 0xF, 0xF, false);
    return __builtin_bit_cast(float, r);
}
// 16-lane reduce: lane (n==15) of each row16 holds the sum.
__device__ __forceinline__ float row16_sum_to_lane15(float p) {
    p += dpp_shr<0x111>(p);  // row_shr:1
    p += dpp_shr<0x112>(p);  // row_shr:2
    p += dpp_shr<0x114>(p);  // row_shr:4
    p += dpp_shr<0x118>(p);  // row_shr:8
    return p;
}

// async 16B global -> LDS
__device__ __forceinline__ void gload16(const void* g, void* l) {
    __builtin_amdgcn_global_load_lds(
        (const __attribute__((address_space(1))) void*)g,
        (__attribute__((address_space(3))) void*)l, 16, 0, 0);
}

// ---------- prep: block 0 = dtype detect; blocks 1.. zero xd ----------
__global__ __launch_bounds__(256) void prep_kernel(const unsigned short* hs, int* flag,
                                                   float* zbuf, int nzero) {
    if (blockIdx.x == 0) {
        __shared__ int cnt[256];
        int c = 0;
        for (int i = threadIdx.x; i < 8192; i += 256) {
            int e = (hs[i] >> 7) & 0xFF;
            if (e == 0 || e == 0xFF || e < 96 || e > 159) c++;
        }
        cnt[threadIdx.x] = c;
        __syncthreads();
        for (int s = 128; s > 0; s >>= 1) {
            if (threadIdx.x < s) cnt[threadIdx.x] += cnt[threadIdx.x + s];
            __syncthreads();
        }
        if (threadIdx.x == 0) *flag = (cnt[0] < 512) ? 1 : 0;
    } else {
        int i = (blockIdx.x - 1) * 256 + threadIdx.x;
        if (i < nzero) zbuf[i] = 0.f;
    }
}

// ---------- fused convert; big bf16 segments skipped (read direct) ----------
struct SrcPtrs { const void* p[10]; };

__device__ __constant__ const size_t SEG_OFF[11] = {
    0, 2097152, 6291456, 6299648, 6301696, 6498304,
    6629376, 6631424, 6664192, 6666240, 8763392
};

__global__ __launch_bounds__(256) void convert_all(SrcPtrs s, bf16* __restrict__ dst,
                                                   const int* __restrict__ flag) {
    size_t e = ((size_t)blockIdx.x * 256 + threadIdx.x) * 4;
    if (e >= SEG_OFF[10]) return;
    int seg = 0;
    #pragma unroll
    for (int i = 1; i < 10; ++i) if (e >= SEG_OFF[i]) seg = i;
    int isbf = *flag;
    if (isbf && (seg == 0 || seg == 1 || seg == 9)) return;
    size_t loc = e - SEG_OFF[seg];
    if (isbf) {
        ushort4 v = ((const ushort4*)s.p[seg])[loc / 4];
        ((ushort4*)(dst + e))[0] = v;
    } else {
        float4 v = ((const float4*)s.p[seg])[loc / 4];
        ushort4 o;
        o.x = bf_bits(v.x); o.y = bf_bits(v.y);
        o.z = bf_bits(v.z); o.w = bf_bits(v.w);
        ((ushort4*)(dst + e))[0] = o;
    }
}

// ---------------- MFMA GEMM: C[m][n] = sum_k A[m][k]*B[n][k], bf16 in, 128x128 tile ----
// OUTMODE: 0 = bf16 store; 2 = f32 split-K partials; 3 = f32 atomicAdd col<96;
//          4 = f32 softplus(v + bias[row])
template <int OUTMODE>
__global__ __launch_bounds__(256) void gemm_mfma(
    const bf16* __restrict__ A, int lda,
    const bf16* __restrict__ Bm, int ldb,
    void* __restrict__ C, int ldc,
    int Kspl, size_t pstride,
    const bf16* __restrict__ bias,
    const bf16* __restrict__ Aalt,
    const bf16* __restrict__ Balt,
    const int* __restrict__ flag)
{
    if (flag && *flag) {
        if (Aalt) A = Aalt;
        if (Balt) Bm = Balt;
    }
    __shared__ __align__(16) __bf16 sA[128 * 32];
    __shared__ __align__(16) __bf16 sB[128 * 32];
    const int tid = threadIdx.x;
    const int m0 = blockIdx.y * 128;
    const int n0 = blockIdx.x * 128;
    const int wid = tid >> 6, ln = tid & 63;
    const int wy = (wid >> 1) * 64, wx = (wid & 1) * 64;
    const int q = ln >> 4, m16 = ln & 15;
    const int kbeg = blockIdx.z * Kspl;

    f32x4 acc[4][4] = {};

    for (int k0 = kbeg; k0 < kbeg + Kspl; k0 += 32) {
        #pragma unroll
        for (int i = 0; i < 2; ++i) {
            int idx = tid + i * 256;
            int r = idx >> 2, c = (idx & 3) * 8;
            gload16(&A[(size_t)(m0 + r) * lda + k0 + c], &sA[idx * 8]);
        }
        #pragma unroll
        for (int i = 0; i < 2; ++i) {
            int idx = tid + i * 256;
            int r = idx >> 2, c = (idx & 3) * 8;
            gload16(&Bm[(size_t)(n0 + r) * ldb + k0 + c], &sB[idx * 8]);
        }
        __syncthreads();
        bf16x8 a[4], b[4];
        #pragma unroll
        for (int i = 0; i < 4; ++i)
            a[i] = *(const bf16x8*)&sA[(wy + i * 16 + m16) * 32 + q * 8];
        #pragma unroll
        for (int j = 0; j < 4; ++j)
            b[j] = *(const bf16x8*)&sB[(wx + j * 16 + m16) * 32 + q * 8];
        #pragma unroll
        for (int i = 0; i < 4; ++i)
            #pragma unroll
            for (int j = 0; j < 4; ++j)
                acc[i][j] = __builtin_amdgcn_mfma_f32_16x16x32_bf16(a[i], b[j], acc[i][j], 0, 0, 0);
        __syncthreads();
    }

    #pragma unroll
    for (int i = 0; i < 4; ++i) {
        #pragma unroll
        for (int j = 0; j < 4; ++j) {
            #pragma unroll
            for (int r = 0; r < 4; ++r) {
                int row = m0 + wy + i * 16 + q * 4 + r;
                int col = n0 + wx + j * 16 + m16;
                size_t idx = (size_t)row * ldc + col;
                float v = acc[i][j][r];
                if constexpr (OUTMODE == 0) {
                    ((bf16*)C)[idx] = __float2bfloat16(v);
                } else if constexpr (OUTMODE == 2) {
                    ((float*)C + blockIdx.z * pstride)[idx] = v;
                } else if constexpr (OUTMODE == 3) {
                    if (col < 96) atomicAdd((float*)C + idx, v);
                } else if constexpr (OUTMODE == 4) {
                    ((float*)C)[idx] = softplus_f(v + to_f(bias[row]));
                }
            }
        }
    }
}

// sum the two split-K partials, store to d_out as bf16 or f32 per flag
__global__ __launch_bounds__(256) void sum_store(
    const float* __restrict__ p0, const float* __restrict__ p1,
    void* __restrict__ out, const int* __restrict__ flag, int n4)
{
    int i = blockIdx.x * 256 + threadIdx.x;
    if (i >= n4) return;
    float4 a = ((const float4*)p0)[i];
    float4 b = ((const float4*)p1)[i];
    float4 sv; sv.x = a.x + b.x; sv.y = a.y + b.y; sv.z = a.z + b.z; sv.w = a.w + b.w;
    if (*flag) {
        ushort4 o;
        o.x = bf_bits(sv.x); o.y = bf_bits(sv.y);
        o.z = bf_bits(sv.z); o.w = bf_bits(sv.w);
        ((ushort4*)out)[i] = o;
    } else {
        ((float4*)out)[i] = sv;
    }
}

// ---------------- transpose (d,row) -> (row,d), 64x64 LDS tiles ----------------
__global__ __launch_bounds__(256) void transpose_bf16(
    const ushort* __restrict__ src,   // (DINNER, ROWS)
    ushort* __restrict__ dst)         // (ROWS, DINNER)
{
    __shared__ ushort t[64][65];
    const int bx = blockIdx.x;        // row-tile
    const int by = blockIdx.y;        // d-tile
    const int tid = threadIdx.x;
    const int lr = tid & 63;
    const int ld = tid >> 6;          // 0..3
    #pragma unroll
    for (int i = 0; i < 16; ++i) {
        int d = ld + i * 4;
        t[d][lr] = src[(size_t)(by * 64 + d) * ROWS + bx * 64 + lr];
    }
    __syncthreads();
    #pragma unroll
    for (int i = 0; i < 16; ++i) {
        int r = ld + i * 4;
        dst[(size_t)(bx * 64 + r) * DINNER + by * 64 + lr] = t[lr][r];
    }
}

// ---------------- xd cvt: xd (2048,96) f32 -> xd_bf bf16 (row-major) ----------------
__global__ __launch_bounds__(256) void xd_cvt(
    const float* __restrict__ xd,
    bf16* __restrict__ xd_bf)
{
    int i = blockIdx.x * 256 + threadIdx.x;   // float4 index; grid sized exactly
    float4 v = ((const float4*)xd)[i];
    ushort4 o;
    o.x = bf_bits(v.x); o.y = bf_bits(v.y);
    o.z = bf_bits(v.z); o.w = bf_bits(v.w);
    ((ushort4*)xd_bf)[i] = o;
}

// ---------------- conv: 8 outputs per thread along L ----------------
__global__ __launch_bounds__(256) void conv_silu_T8(
    const bf16* __restrict__ xzT,
    const bf16* __restrict__ w,
    const bf16* __restrict__ bias,
    bf16* __restrict__ utT)
{
    int t = blockIdx.x * 256 + threadIdx.x;
    int r0 = (t * 8) & (ROWS - 1);
    int d = t >> 8;

    const ushort* xp = (const ushort*)xzT + (size_t)d * ROWS + r0;
    float x[11];
    us8 cur = *(const us8*)xp;
    #pragma unroll
    for (int j = 0; j < 8; ++j) x[3 + j] = bfu(cur[j]);
    if ((r0 & (SEQLEN - 1)) != 0) {
        ushort4 pv = *(const ushort4*)(xp - 4);
        x[0] = bfu(pv.y); x[1] = bfu(pv.z); x[2] = bfu(pv.w);
    } else {
        x[0] = x[1] = x[2] = 0.f;
    }

    ushort4 wv = *(const ushort4*)((const ushort*)w + d * 4);
    float w0 = bfu(wv.x), w1 = bfu(wv.y), w2 = bfu(wv.z), w3 = bfu(wv.w);
    float bv = to_f(bias[d]);

    us8 o;
    #pragma unroll
    for (int j = 0; j < 8; ++j) {
        float acc = bv;
        acc = fmaf(x[j],     w0, acc);
        acc = fmaf(x[j + 1], w1, acc);
        acc = fmaf(x[j + 2], w2, acc);
        acc = fmaf(x[j + 3], w3, acc);
        o[j] = bf_bits(silu_f(acc));
    }
    *(us8*)((ushort*)utT + (size_t)d * ROWS + r0) = o;
}

// ---------------- scan v15: coalesced B/C with register-cheap addressing ----------
// Block = 1024 thr = 16 L-chunks(waves) x 4 d x 16 n; grid = BATCH * DINNER/4.
// B/C read from row-major xd (row, 96). ONE induction pointer per phase bumped
// by 384 floats/iter; all 8 loads use compile-time immediate offsets
// (0,64,384,448,768,832,1152,1216 B <= 13-bit signed global offset), so no
// per-lane 64-bit address mads, no prefetch arrays -> no spill (v14 lesson:
// VGPR 64 + 90MB scratch writes). dv/uv keep the cheap v12 register prefetch.
#define SCHUNK 16
#define SSTEPS (SEQLEN / SCHUNK)   // 64
__global__ __launch_bounds__(1024) void scan_kernel15(
    const float* __restrict__ deltaT,  // (DINNER, ROWS) f32
    const bf16*  __restrict__ utT,     // (DINNER, ROWS)
    const float* __restrict__ xd96,    // (ROWS, 96) f32: col 64+n = B_n, 80+n = C_n
    const bf16*  __restrict__ xzT,     // (4096, ROWS): z at row DINNER+d
    const bf16*  __restrict__ A_log,   // (DINNER,16)
    const bf16*  __restrict__ Dp,      // (DINNER,)
    bf16* __restrict__ outzT)          // (DINNER, ROWS)
{
    __shared__ float2 sHP[SCHUNK][64];
    __shared__ float sQ[SCHUNK][4][68];   // 68 = 64 + 4 pad (bank spread)
    __shared__ float sS[SCHUNK][4][68];
    const int tid = threadIdx.x;
    const int c = tid >> 6;            // wave-uniform chunk id
    const int w = tid & 63;
    const int dcol = (tid >> 4) & 3;
    const int n = tid & 15;
    const int b = blockIdx.x >> 9;
    const int d = ((blockIdx.x & 511) << 2) + dcol;
    const int row0 = b * SEQLEN + c * SSTEPS;

    const float Aa2 = -expf(to_f(A_log[d * DSTATE + n])) * LOG2E;
    const float Dv = to_f(Dp[d]);

    const float*  dp = deltaT + (size_t)d * ROWS + row0;
    const ushort* up = (const ushort*)utT + (size_t)d * ROWS + row0;
    const ushort* zp = (const ushort*)xzT + (size_t)(DINNER + d) * ROWS + row0;
    const float*  bcp = xd96 + (size_t)row0 * 96 + 64 + n;  // B at +0, C at +16

    // ---- phase 1: local scan; produce q_t (lane15) and S_t ----
    // NOTE: dv/uv last-iteration prefetch reads 16B past the logical chunk;
    // both streams are interior workspace regions followed by more workspace,
    // so the over-read stays inside d_ws and the values are never used.
    float hl = 0.f, sd = 0.f;
    float4  dv4 = *(const float4*)(dp);
    ushort4 uv4 = *(const ushort4*)(up);
    const float* bct = bcp;
    for (int i0 = 0; i0 < SSTEPS; i0 += 4) {
        float4  dvn = *(const float4*)(dp + i0 + 4);
        ushort4 uvn = *(const ushort4*)(up + i0 + 4);
        float Bv[4], Cv[4];
        Bv[0] = bct[0];   Cv[0] = bct[16];
        Bv[1] = bct[96];  Cv[1] = bct[112];
        Bv[2] = bct[192]; Cv[2] = bct[208];
        Bv[3] = bct[288]; Cv[3] = bct[304];
        bct += 384;
        float dv[4] = {dv4.x, dv4.y, dv4.z, dv4.w};
        float uv[4] = {bfu(uv4.x), bfu(uv4.y), bfu(uv4.z), bfu(uv4.w)};
        float qv[4], sv[4];
        #pragma unroll
        for (int j = 0; j < 4; ++j) {
            sd += dv[j];
            sv[j] = sd;
            float a = fexp2(dv[j] * Aa2);
            hl = fmaf(a, hl, dv[j] * Bv[j] * uv[j]);
            float p = hl * Cv[j];
            p = row16_sum_to_lane15(p);
            qv[j] = fmaf(uv[j], Dv, p);
        }
        if (n == 15) {
            float4 qo; qo.x = qv[0]; qo.y = qv[1]; qo.z = qv[2]; qo.w = qv[3];
            float4 so; so.x = sv[0]; so.y = sv[1]; so.z = sv[2]; so.w = sv[3];
            *(float4*)&sQ[c][dcol][i0] = qo;
            *(float4*)&sS[c][dcol][i0] = so;
        }
        dv4 = dvn; uv4 = uvn;
    }
    sHP[c][w] = make_float2(hl, fexp2(sd * Aa2));
    __syncthreads();

    // ---- phase 2: fold preceding chunk summaries (1 b64 read / step) ----
    float hin = 0.f;
    for (int cc = 0; cc < c; ++cc) {
        float2 hp = sHP[cc][w];
        hin = fmaf(hp.y, hin, hp.x);
    }

    // ---- phase 3: chain-free correction; C reload via immediate offsets ----
    ushort4 zv4 = *(const ushort4*)(zp);
    bct = bcp;
    for (int i0 = 0; i0 < SSTEPS; i0 += 4) {
        ushort4 zvn = *(const ushort4*)(zp + i0 + 4);
        float Cv[4];
        Cv[0] = bct[16];  Cv[1] = bct[112];
        Cv[2] = bct[208]; Cv[3] = bct[304];
        bct += 384;
        float4 q4 = *(const float4*)&sQ[c][dcol][i0];
        float4 s4 = *(const float4*)&sS[c][dcol][i0];
        float ss[4] = {s4.x, s4.y, s4.z, s4.w};
        float qq[4] = {q4.x, q4.y, q4.z, q4.w};
        float zv[4] = {bfu(zv4.x), bfu(zv4.y), bfu(zv4.z), bfu(zv4.w)};
        float y[4];
        #pragma unroll
        for (int j = 0; j < 4; ++j) {
            float e = fexp2(ss[j] * Aa2);
            float p = (hin * e) * Cv[j];
            p = row16_sum_to_lane15(p);
            y[j] = qq[j] + p;
        }
        if (n == 15) {
            ushort4 o;
            o.x = bf_bits(y[0] * silu_f(zv[0]));
            o.y = bf_bits(y[1] * silu_f(zv[1]));
            o.z = bf_bits(y[2] * silu_f(zv[2]));
            o.w = bf_bits(y[3] * silu_f(zv[3]));
            *(ushort4*)((ushort*)outzT + (size_t)d * ROWS + row0 + i0) = o;
        }
        zv4 = zvn;
    }
}

extern "C" void kernel_launch(void* const* d_in, const int* in_sizes, int n_in,
                              void* d_out, int out_size, void* d_ws, size_t ws_size,
                              hipStream_t stream) {
    static const size_t SZ[10] = {
        (size_t)BATCH * SEQLEN * DMODEL,        // hidden_states
        (size_t)2 * DINNER * DMODEL,            // in_proj_w
        (size_t)DINNER * 4,                     // conv1d_w
        (size_t)DINNER,                         // conv1d_b
        (size_t)(DTRANK + 2 * DSTATE) * DINNER, // x_proj_w
        (size_t)DINNER * DTRANK,                // dt_proj_w
        (size_t)DINNER,                         // dt_proj_b
        (size_t)DINNER * DSTATE,                // A_log
        (size_t)DINNER,                         // D_param
        (size_t)DMODEL * DINNER                 // out_proj_w
    };
    size_t tot_in = 0;
    for (int i = 0; i < 10; ++i) tot_in += SZ[i];

    char* p = (char*)d_ws;
    int* flag = (int*)p;                     p += 64;
    bf16* inb = (bf16*)p;                    p += tot_in * 2;
    bf16* xzT = (bf16*)p;                    p += (size_t)4096 * ROWS * 2;
    bf16* utT = (bf16*)p;                    p += (size_t)DINNER * ROWS * 2;
    bf16* ut  = (bf16*)p;                    p += (size_t)ROWS * DINNER * 2;
    float* xd = (float*)p;                   p += (size_t)ROWS * 96 * 4;
    bf16* xd_bf = (bf16*)p;                  p += (size_t)ROWS * 96 * 2;
    float* deltaT = (float*)p;               p += (size_t)DINNER * ROWS * 4;
    bf16* outzT = (bf16*)p;                  p += (size_t)DINNER * ROWS * 2;
    bf16* outz = (bf16*)p;                   p += (size_t)ROWS * DINNER * 2;
    float* part = (float*)p;                 p += (size_t)2 * ROWS * DMODEL * 4;
    size_t needed = (size_t)(p - (char*)d_ws);
    if (ws_size < needed) return;

    dim3 blk(256);

    // 0) detect dtype + zero xd (for atomic accumulation)
    prep_kernel<<<1 + (ROWS * 96 + 255) / 256, blk, 0, stream>>>(
        (const unsigned short*)d_in[0], flag, xd, ROWS * 96);

    bf16* inp[10];
    {
        size_t off = 0;
        for (int i = 0; i < 10; ++i) { inp[i] = inb + off; off += SZ[i]; }
    }
    SrcPtrs sp;
    for (int i = 0; i < 10; ++i) sp.p[i] = d_in[i];
    convert_all<<<(int)((tot_in / 4 + 255) / 256), blk, 0, stream>>>(sp, inb, flag);

    const bf16* hs        = inp[0];
    const bf16* in_proj_w = inp[1];
    const bf16* conv_w    = inp[2];
    const bf16* conv_b    = inp[3];
    const bf16* x_proj_w  = inp[4];
    const bf16* dt_proj_w = inp[5];
    const bf16* dt_proj_b = inp[6];
    const bf16* A_log     = inp[7];
    const bf16* Dp        = inp[8];
    const bf16* out_proj_w= inp[9];

    // 1) xzT = (hs @ in_proj_w^T)^T : dual-ptr — reads d_in directly when bf16
    gemm_mfma<0><<<dim3(ROWS / 128, 4096 / 128, 1), blk, 0, stream>>>(
        in_proj_w, DMODEL, hs, DMODEL, xzT, ROWS, DMODEL, 0, nullptr,
        (const bf16*)d_in[1], (const bf16*)d_in[0], flag);

    // 2) utT = silu(causal depthwise conv along L), d-major
    conv_silu_T8<<<(DINNER * ROWS / 8) / 256, blk, 0, stream>>>(xzT, conv_w, conv_b, utT);

    // 2b) ut = utT^T (row-major, for MFMA x_proj)
    transpose_bf16<<<dim3(ROWS / 64, DINNER / 64), blk, 0, stream>>>(
        (const ushort*)utT, (ushort*)ut);

    // 3) xd[row][r] = sum_d ut[row][d] * x_proj_w[r][d]  (MFMA, split-K=4, atomic f32)
    gemm_mfma<3><<<dim3(1, ROWS / 128, 4), blk, 0, stream>>>(
        ut, DINNER, x_proj_w, DINNER, xd, 96, DINNER / 4, 0, nullptr,
        nullptr, nullptr, nullptr);

    // 3b) xd_bf = bf16(xd)  (row-major, dt GEMM operand); scan reads xd directly
    xd_cvt<<<ROWS * 96 / 4 / 256, blk, 0, stream>>>(xd, xd_bf);

    // 4) deltaT[d][row] = softplus(sum_r dtw[d][r]*xd[row][r] + dtb[d])  (MFMA K=64)
    gemm_mfma<4><<<dim3(ROWS / 128, DINNER / 128, 1), blk, 0, stream>>>(
        dt_proj_w, DTRANK, xd_bf, 96, deltaT, ROWS, DTRANK, 0, dt_proj_b,
        nullptr, nullptr, nullptr);

    // 5) chunk-parallel selective scan -> outzT (d-major, full-line writes)
    scan_kernel15<<<BATCH * (DINNER / 4), dim3(1024), 0, stream>>>(
        deltaT, utT, xd, xzT, A_log, Dp, outzT);

    // 5b) outz = outzT^T (row-major for gemm6)
    transpose_bf16<<<dim3(ROWS / 64, DINNER / 64), blk, 0, stream>>>(
        (const ushort*)outzT, (ushort*)outz);

    // 6) out = outz @ out_proj_w^T  (MFMA split-K=2 -> f32 partials; dual-ptr B)
    gemm_mfma<2><<<dim3(DMODEL / 128, ROWS / 128, 2), blk, 0, stream>>>(
        outz, DINNER, out_proj_w, DINNER, part, DMODEL, DINNER / 2, (size_t)ROWS * DMODEL,
        nullptr, nullptr, (const bf16*)d_in[9], flag);

    // 6b) out = cvt(part0 + part1)
    sum_store<<<(ROWS * DMODEL / 4 + 255) / 256, blk, 0, stream>>>(
        part, part + (size_t)ROWS * DMODEL, d_out, flag, ROWS * DMODEL / 4);
}

// Round 6
// 294.203 us; speedup vs baseline: 1.2660x; 1.0229x over previous
//
#include <hip/hip_runtime.h>
#include <hip/hip_bf16.h>

// Shapes: B=2, L=1024, D_MODEL=1024, D_INNER=2048, D_STATE=16, D_CONV=4, DT_RANK=64
#define BATCH 2
#define SEQLEN 1024
#define DMODEL 1024
#define DINNER 2048
#define DSTATE 16
#define DTRANK 64
#define ROWS (BATCH * SEQLEN) // 2048
#define LOG2E 1.44269504088896340736f

using bf16 = __hip_bfloat16;
typedef __bf16 bf16x8 __attribute__((ext_vector_type(8)));
typedef float f32x4 __attribute__((ext_vector_type(4)));
typedef unsigned short us8 __attribute__((ext_vector_type(8)));

__device__ __forceinline__ float to_f(float x) { return x; }
__device__ __forceinline__ float to_f(bf16 x) { return __bfloat162float(x); }

__device__ __forceinline__ float fexp2(float x) { return __builtin_amdgcn_exp2f(x); }

__device__ __forceinline__ float bfu(unsigned short u) {
    union { unsigned int i; float f; } v;
    v.i = ((unsigned int)u) << 16;
    return v.f;
}

__device__ __forceinline__ unsigned short bf_bits(float x) {
    bf16 h = __float2bfloat16(x);
    union { bf16 b; unsigned short u; } cv;
    cv.b = h;
    return cv.u;
}

__device__ __forceinline__ float softplus_f(float x) {
    return fmaxf(x, 0.f) + log1pf(expf(-fabsf(x)));
}
// fast silu
__device__ __forceinline__ float silu_f(float x) {
    return x * __builtin_amdgcn_rcpf(1.f + fexp2(-x * LOG2E));
}

// DPP row_shr move (within 16-lane row); invalid source lanes contribute 0.
template <int CTRL>
__device__ __forceinline__ float dpp_shr(float x) {
    int r = __builtin_amdgcn_update_dpp(0, __builtin_bit_cast(int, x), CTRL, 0xF, 0xF, false);
    return __builtin_bit_cast(float, r);
}
// 16-lane reduce: lane (n==15) of each row16 holds the sum.
__device__ __forceinline__ float row16_sum_to_lane15(float p) {
    p += dpp_shr<0x111>(p);  // row_shr:1
    p += dpp_shr<0x112>(p);  // row_shr:2
    p += dpp_shr<0x114>(p);  // row_shr:4
    p += dpp_shr<0x118>(p);  // row_shr:8
    return p;
}

// async 16B global -> LDS
__device__ __forceinline__ void gload16(const void* g, void* l) {
    __builtin_amdgcn_global_load_lds(
        (const __attribute__((address_space(1))) void*)g,
        (__attribute__((address_space(3))) void*)l, 16, 0, 0);
}

// ---------- prep: block 0 = dtype detect; blocks 1.. zero xd ----------
__global__ __launch_bounds__(256) void prep_kernel(const unsigned short* hs, int* flag,
                                                   float* zbuf, int nzero) {
    if (blockIdx.x == 0) {
        __shared__ int cnt[256];
        int c = 0;
        for (int i = threadIdx.x; i < 8192; i += 256) {
            int e = (hs[i] >> 7) & 0xFF;
            if (e == 0 || e == 0xFF || e < 96 || e > 159) c++;
        }
        cnt[threadIdx.x] = c;
        __syncthreads();
        for (int s = 128; s > 0; s >>= 1) {
            if (threadIdx.x < s) cnt[threadIdx.x] += cnt[threadIdx.x + s];
            __syncthreads();
        }
        if (threadIdx.x == 0) *flag = (cnt[0] < 512) ? 1 : 0;
    } else {
        int i = (blockIdx.x - 1) * 256 + threadIdx.x;
        if (i < nzero) zbuf[i] = 0.f;
    }
}

// ---------- fused convert; big bf16 segments skipped (read direct) ----------
struct SrcPtrs { const void* p[10]; };

__device__ __constant__ const size_t SEG_OFF[11] = {
    0, 2097152, 6291456, 6299648, 6301696, 6498304,
    6629376, 6631424, 6664192, 6666240, 8763392
};

__global__ __launch_bounds__(256) void convert_all(SrcPtrs s, bf16* __restrict__ dst,
                                                   const int* __restrict__ flag) {
    size_t e = ((size_t)blockIdx.x * 256 + threadIdx.x) * 4;
    if (e >= SEG_OFF[10]) return;
    int seg = 0;
    #pragma unroll
    for (int i = 1; i < 10; ++i) if (e >= SEG_OFF[i]) seg = i;
    int isbf = *flag;
    if (isbf && (seg == 0 || seg == 1 || seg == 9)) return;
    size_t loc = e - SEG_OFF[seg];
    if (isbf) {
        ushort4 v = ((const ushort4*)s.p[seg])[loc / 4];
        ((ushort4*)(dst + e))[0] = v;
    } else {
        float4 v = ((const float4*)s.p[seg])[loc / 4];
        ushort4 o;
        o.x = bf_bits(v.x); o.y = bf_bits(v.y);
        o.z = bf_bits(v.z); o.w = bf_bits(v.w);
        ((ushort4*)(dst + e))[0] = o;
    }
}

// ---------------- MFMA GEMM: C[m][n] = sum_k A[m][k]*B[n][k], bf16 in, 128x128 tile ----
// OUTMODE: 0 = bf16 store; 2 = f32 split-K partials; 3 = f32 atomicAdd col<96;
//          4 = f32 softplus(v + bias[row])
template <int OUTMODE>
__global__ __launch_bounds__(256) void gemm_mfma(
    const bf16* __restrict__ A, int lda,
    const bf16* __restrict__ Bm, int ldb,
    void* __restrict__ C, int ldc,
    int Kspl, size_t pstride,
    const bf16* __restrict__ bias,
    const bf16* __restrict__ Aalt,
    const bf16* __restrict__ Balt,
    const int* __restrict__ flag)
{
    if (flag && *flag) {
        if (Aalt) A = Aalt;
        if (Balt) Bm = Balt;
    }
    __shared__ __align__(16) __bf16 sA[128 * 32];
    __shared__ __align__(16) __bf16 sB[128 * 32];
    const int tid = threadIdx.x;
    const int m0 = blockIdx.y * 128;
    const int n0 = blockIdx.x * 128;
    const int wid = tid >> 6, ln = tid & 63;
    const int wy = (wid >> 1) * 64, wx = (wid & 1) * 64;
    const int q = ln >> 4, m16 = ln & 15;
    const int kbeg = blockIdx.z * Kspl;

    f32x4 acc[4][4] = {};

    for (int k0 = kbeg; k0 < kbeg + Kspl; k0 += 32) {
        #pragma unroll
        for (int i = 0; i < 2; ++i) {
            int idx = tid + i * 256;
            int r = idx >> 2, c = (idx & 3) * 8;
            gload16(&A[(size_t)(m0 + r) * lda + k0 + c], &sA[idx * 8]);
        }
        #pragma unroll
        for (int i = 0; i < 2; ++i) {
            int idx = tid + i * 256;
            int r = idx >> 2, c = (idx & 3) * 8;
            gload16(&Bm[(size_t)(n0 + r) * ldb + k0 + c], &sB[idx * 8]);
        }
        __syncthreads();
        bf16x8 a[4], b[4];
        #pragma unroll
        for (int i = 0; i < 4; ++i)
            a[i] = *(const bf16x8*)&sA[(wy + i * 16 + m16) * 32 + q * 8];
        #pragma unroll
        for (int j = 0; j < 4; ++j)
            b[j] = *(const bf16x8*)&sB[(wx + j * 16 + m16) * 32 + q * 8];
        #pragma unroll
        for (int i = 0; i < 4; ++i)
            #pragma unroll
            for (int j = 0; j < 4; ++j)
                acc[i][j] = __builtin_amdgcn_mfma_f32_16x16x32_bf16(a[i], b[j], acc[i][j], 0, 0, 0);
        __syncthreads();
    }

    #pragma unroll
    for (int i = 0; i < 4; ++i) {
        #pragma unroll
        for (int j = 0; j < 4; ++j) {
            #pragma unroll
            for (int r = 0; r < 4; ++r) {
                int row = m0 + wy + i * 16 + q * 4 + r;
                int col = n0 + wx + j * 16 + m16;
                size_t idx = (size_t)row * ldc + col;
                float v = acc[i][j][r];
                if constexpr (OUTMODE == 0) {
                    ((bf16*)C)[idx] = __float2bfloat16(v);
                } else if constexpr (OUTMODE == 2) {
                    ((float*)C + blockIdx.z * pstride)[idx] = v;
                } else if constexpr (OUTMODE == 3) {
                    if (col < 96) atomicAdd((float*)C + idx, v);
                } else if constexpr (OUTMODE == 4) {
                    ((float*)C)[idx] = softplus_f(v + to_f(bias[row]));
                }
            }
        }
    }
}

// sum the two split-K partials, store to d_out as bf16 or f32 per flag
__global__ __launch_bounds__(256) void sum_store(
    const float* __restrict__ p0, const float* __restrict__ p1,
    void* __restrict__ out, const int* __restrict__ flag, int n4)
{
    int i = blockIdx.x * 256 + threadIdx.x;
    if (i >= n4) return;
    float4 a = ((const float4*)p0)[i];
    float4 b = ((const float4*)p1)[i];
    float4 sv; sv.x = a.x + b.x; sv.y = a.y + b.y; sv.z = a.z + b.z; sv.w = a.w + b.w;
    if (*flag) {
        ushort4 o;
        o.x = bf_bits(sv.x); o.y = bf_bits(sv.y);
        o.z = bf_bits(sv.z); o.w = bf_bits(sv.w);
        ((ushort4*)out)[i] = o;
    } else {
        ((float4*)out)[i] = sv;
    }
}

// ---------------- transpose (d,row) -> (row,d), 64x64 LDS tiles ----------------
__global__ __launch_bounds__(256) void transpose_bf16(
    const ushort* __restrict__ src,   // (DINNER, ROWS)
    ushort* __restrict__ dst)         // (ROWS, DINNER)
{
    __shared__ ushort t[64][65];
    const int bx = blockIdx.x;        // row-tile
    const int by = blockIdx.y;        // d-tile
    const int tid = threadIdx.x;
    const int lr = tid & 63;
    const int ld = tid >> 6;          // 0..3
    #pragma unroll
    for (int i = 0; i < 16; ++i) {
        int d = ld + i * 4;
        t[d][lr] = src[(size_t)(by * 64 + d) * ROWS + bx * 64 + lr];
    }
    __syncthreads();
    #pragma unroll
    for (int i = 0; i < 16; ++i) {
        int r = ld + i * 4;
        dst[(size_t)(bx * 64 + r) * DINNER + by * 64 + lr] = t[lr][r];
    }
}

// ---------------- xd cvt: xd (2048,96) f32 -> xd_bf bf16 (row-major) ----------------
__global__ __launch_bounds__(256) void xd_cvt(
    const float* __restrict__ xd,
    bf16* __restrict__ xd_bf)
{
    int i = blockIdx.x * 256 + threadIdx.x;   // float4 index; grid sized exactly
    float4 v = ((const float4*)xd)[i];
    ushort4 o;
    o.x = bf_bits(v.x); o.y = bf_bits(v.y);
    o.z = bf_bits(v.z); o.w = bf_bits(v.w);
    ((ushort4*)xd_bf)[i] = o;
}

// ---------------- conv: 8 outputs per thread along L ----------------
__global__ __launch_bounds__(256) void conv_silu_T8(
    const bf16* __restrict__ xzT,
    const bf16* __restrict__ w,
    const bf16* __restrict__ bias,
    bf16* __restrict__ utT)
{
    int t = blockIdx.x * 256 + threadIdx.x;
    int r0 = (t * 8) & (ROWS - 1);
    int d = t >> 8;

    const ushort* xp = (const ushort*)xzT + (size_t)d * ROWS + r0;
    float x[11];
    us8 cur = *(const us8*)xp;
    #pragma unroll
    for (int j = 0; j < 8; ++j) x[3 + j] = bfu(cur[j]);
    if ((r0 & (SEQLEN - 1)) != 0) {
        ushort4 pv = *(const ushort4*)(xp - 4);
        x[0] = bfu(pv.y); x[1] = bfu(pv.z); x[2] = bfu(pv.w);
    } else {
        x[0] = x[1] = x[2] = 0.f;
    }

    ushort4 wv = *(const ushort4*)((const ushort*)w + d * 4);
    float w0 = bfu(wv.x), w1 = bfu(wv.y), w2 = bfu(wv.z), w3 = bfu(wv.w);
    float bv = to_f(bias[d]);

    us8 o;
    #pragma unroll
    for (int j = 0; j < 8; ++j) {
        float acc = bv;
        acc = fmaf(x[j],     w0, acc);
        acc = fmaf(x[j + 1], w1, acc);
        acc = fmaf(x[j + 2], w2, acc);
        acc = fmaf(x[j + 3], w3, acc);
        o[j] = bf_bits(silu_f(acc));
    }
    *(us8*)((ushort*)utT + (size_t)d * ROWS + r0) = o;
}

// ---------------- scan v16: cheap-pass / full-pass, 512-thr wave-uniform chunks ----
// Block = 512 thr = 8 L-chunks(waves) x 4 d x 16 n; grid = BATCH * DINNER/4 = 1024.
// Pass A: h-chain + delta-sum only (no C, no reduce, no per-t LDS) -> chunk summary.
// Fold (<=7 iters). Pass B: full rescan seeded with hin, producing y directly
// (identical math to the verified v11 phase-3). Removes sQ/sS (43K -> 4K LDS),
// the per-t q/S stores+loads, and one exp2+reduce redundancy chain.
// 8-wave blocks -> 4 resident blocks/CU (wave cap 32): barriers/fold of one
// block overlap with 3 others. Chunks are wave-uniform (R3 lesson).
#define SCHUNK 8
#define SSTEPS (SEQLEN / SCHUNK)   // 128
__global__ __launch_bounds__(512) void scan_kernel16(
    const float* __restrict__ deltaT,  // (DINNER, ROWS) f32
    const bf16*  __restrict__ utT,     // (DINNER, ROWS)
    const float* __restrict__ xd96,    // (ROWS, 96) f32: col 64+n = B_n, 80+n = C_n
    const bf16*  __restrict__ xzT,     // (4096, ROWS): z at row DINNER+d
    const bf16*  __restrict__ A_log,   // (DINNER,16)
    const bf16*  __restrict__ Dp,      // (DINNER,)
    bf16* __restrict__ outzT)          // (DINNER, ROWS)
{
    __shared__ float2 sHP[SCHUNK][64];
    const int tid = threadIdx.x;
    const int c = tid >> 6;            // wave-uniform chunk id 0..7
    const int w = tid & 63;
    const int dcol = (tid >> 4) & 3;
    const int n = tid & 15;
    const int b = blockIdx.x >> 9;
    const int d = ((blockIdx.x & 511) << 2) + dcol;
    const int row0 = b * SEQLEN + c * SSTEPS;

    const float Aa2 = -expf(to_f(A_log[d * DSTATE + n])) * LOG2E;
    const float Dv = to_f(Dp[d]);

    const float*  dp = deltaT + (size_t)d * ROWS + row0;
    const ushort* up = (const ushort*)utT + (size_t)d * ROWS + row0;
    const ushort* zp = (const ushort*)xzT + (size_t)(DINNER + d) * ROWS + row0;
    const float*  bcp = xd96 + (size_t)row0 * 96 + 64 + n;  // B at +0, C at +16

    // ---- pass A: chunk summary only (h-chain + sum of delta) ----
    // NOTE: dv/uv last-iteration prefetch reads 16B past the logical chunk;
    // all streams are interior workspace regions followed by more workspace,
    // so the over-read stays inside d_ws and the values are never used.
    float hl = 0.f, sd = 0.f;
    float4  dv4 = *(const float4*)(dp);
    ushort4 uv4 = *(const ushort4*)(up);
    const float* bct = bcp;
    for (int i0 = 0; i0 < SSTEPS; i0 += 4) {
        float4  dvn = *(const float4*)(dp + i0 + 4);
        ushort4 uvn = *(const ushort4*)(up + i0 + 4);
        float Bv[4];
        Bv[0] = bct[0];
        Bv[1] = bct[96];
        Bv[2] = bct[192];
        Bv[3] = bct[288];
        bct += 384;
        float dv[4] = {dv4.x, dv4.y, dv4.z, dv4.w};
        float uv[4] = {bfu(uv4.x), bfu(uv4.y), bfu(uv4.z), bfu(uv4.w)};
        #pragma unroll
        for (int j = 0; j < 4; ++j) {
            sd += dv[j];
            float a = fexp2(dv[j] * Aa2);
            hl = fmaf(a, hl, dv[j] * Bv[j] * uv[j]);
        }
        dv4 = dvn; uv4 = uvn;
    }
    sHP[c][w] = make_float2(hl, fexp2(sd * Aa2));
    __syncthreads();

    // ---- fold preceding chunk summaries (<= 7 iters, wave-uniform) ----
    float hin = 0.f;
    for (int cc = 0; cc < c; ++cc) {
        float2 hp = sHP[cc][w];
        hin = fmaf(hp.y, hin, hp.x);
    }

    // ---- pass B: full rescan seeded with hin; y produced directly ----
    float h = hin;
    dv4 = *(const float4*)(dp);
    uv4 = *(const ushort4*)(up);
    ushort4 zv4 = *(const ushort4*)(zp);
    bct = bcp;
    for (int i0 = 0; i0 < SSTEPS; i0 += 4) {
        float4  dvn = *(const float4*)(dp + i0 + 4);
        ushort4 uvn = *(const ushort4*)(up + i0 + 4);
        ushort4 zvn = *(const ushort4*)(zp + i0 + 4);
        float Bv[4], Cv[4];
        Bv[0] = bct[0];   Cv[0] = bct[16];
        Bv[1] = bct[96];  Cv[1] = bct[112];
        Bv[2] = bct[192]; Cv[2] = bct[208];
        Bv[3] = bct[288]; Cv[3] = bct[304];
        bct += 384;
        float dv[4] = {dv4.x, dv4.y, dv4.z, dv4.w};
        float uv[4] = {bfu(uv4.x), bfu(uv4.y), bfu(uv4.z), bfu(uv4.w)};
        float zv[4] = {bfu(zv4.x), bfu(zv4.y), bfu(zv4.z), bfu(zv4.w)};
        float y[4];
        #pragma unroll
        for (int j = 0; j < 4; ++j) {
            float a = fexp2(dv[j] * Aa2);
            h = fmaf(a, h, dv[j] * Bv[j] * uv[j]);
            float p = h * Cv[j];
            p = row16_sum_to_lane15(p);
            y[j] = fmaf(uv[j], Dv, p);
        }
        if (n == 15) {
            ushort4 o;
            o.x = bf_bits(y[0] * silu_f(zv[0]));
            o.y = bf_bits(y[1] * silu_f(zv[1]));
            o.z = bf_bits(y[2] * silu_f(zv[2]));
            o.w = bf_bits(y[3] * silu_f(zv[3]));
            *(ushort4*)((ushort*)outzT + (size_t)d * ROWS + row0 + i0) = o;
        }
        dv4 = dvn; uv4 = uvn; zv4 = zvn;
    }
}

extern "C" void kernel_launch(void* const* d_in, const int* in_sizes, int n_in,
                              void* d_out, int out_size, void* d_ws, size_t ws_size,
                              hipStream_t stream) {
    static const size_t SZ[10] = {
        (size_t)BATCH * SEQLEN * DMODEL,        // hidden_states
        (size_t)2 * DINNER * DMODEL,            // in_proj_w
        (size_t)DINNER * 4,                     // conv1d_w
        (size_t)DINNER,                         // conv1d_b
        (size_t)(DTRANK + 2 * DSTATE) * DINNER, // x_proj_w
        (size_t)DINNER * DTRANK,                // dt_proj_w
        (size_t)DINNER,                         // dt_proj_b
        (size_t)DINNER * DSTATE,                // A_log
        (size_t)DINNER,                         // D_param
        (size_t)DMODEL * DINNER                 // out_proj_w
    };
    size_t tot_in = 0;
    for (int i = 0; i < 10; ++i) tot_in += SZ[i];

    char* p = (char*)d_ws;
    int* flag = (int*)p;                     p += 64;
    bf16* inb = (bf16*)p;                    p += tot_in * 2;
    bf16* xzT = (bf16*)p;                    p += (size_t)4096 * ROWS * 2;
    bf16* utT = (bf16*)p;                    p += (size_t)DINNER * ROWS * 2;
    bf16* ut  = (bf16*)p;                    p += (size_t)ROWS * DINNER * 2;
    float* xd = (float*)p;                   p += (size_t)ROWS * 96 * 4;
    bf16* xd_bf = (bf16*)p;                  p += (size_t)ROWS * 96 * 2;
    float* deltaT = (float*)p;               p += (size_t)DINNER * ROWS * 4;
    bf16* outzT = (bf16*)p;                  p += (size_t)DINNER * ROWS * 2;
    bf16* outz = (bf16*)p;                   p += (size_t)ROWS * DINNER * 2;
    float* part = (float*)p;                 p += (size_t)2 * ROWS * DMODEL * 4;
    size_t needed = (size_t)(p - (char*)d_ws);
    if (ws_size < needed) return;

    dim3 blk(256);

    // 0) detect dtype + zero xd (for atomic accumulation)
    prep_kernel<<<1 + (ROWS * 96 + 255) / 256, blk, 0, stream>>>(
        (const unsigned short*)d_in[0], flag, xd, ROWS * 96);

    bf16* inp[10];
    {
        size_t off = 0;
        for (int i = 0; i < 10; ++i) { inp[i] = inb + off; off += SZ[i]; }
    }
    SrcPtrs sp;
    for (int i = 0; i < 10; ++i) sp.p[i] = d_in[i];
    convert_all<<<(int)((tot_in / 4 + 255) / 256), blk, 0, stream>>>(sp, inb, flag);

    const bf16* hs        = inp[0];
    const bf16* in_proj_w = inp[1];
    const bf16* conv_w    = inp[2];
    const bf16* conv_b    = inp[3];
    const bf16* x_proj_w  = inp[4];
    const bf16* dt_proj_w = inp[5];
    const bf16* dt_proj_b = inp[6];
    const bf16* A_log     = inp[7];
    const bf16* Dp        = inp[8];
    const bf16* out_proj_w= inp[9];

    // 1) xzT = (hs @ in_proj_w^T)^T : dual-ptr — reads d_in directly when bf16
    gemm_mfma<0><<<dim3(ROWS / 128, 4096 / 128, 1), blk, 0, stream>>>(
        in_proj_w, DMODEL, hs, DMODEL, xzT, ROWS, DMODEL, 0, nullptr,
        (const bf16*)d_in[1], (const bf16*)d_in[0], flag);

    // 2) utT = silu(causal depthwise conv along L), d-major
    conv_silu_T8<<<(DINNER * ROWS / 8) / 256, blk, 0, stream>>>(xzT, conv_w, conv_b, utT);

    // 2b) ut = utT^T (row-major, for MFMA x_proj)
    transpose_bf16<<<dim3(ROWS / 64, DINNER / 64), blk, 0, stream>>>(
        (const ushort*)utT, (ushort*)ut);

    // 3) xd[row][r] = sum_d ut[row][d] * x_proj_w[r][d]  (MFMA, split-K=4, atomic f32)
    gemm_mfma<3><<<dim3(1, ROWS / 128, 4), blk, 0, stream>>>(
        ut, DINNER, x_proj_w, DINNER, xd, 96, DINNER / 4, 0, nullptr,
        nullptr, nullptr, nullptr);

    // 3b) xd_bf = bf16(xd)  (row-major, dt GEMM operand); scan reads xd directly
    xd_cvt<<<ROWS * 96 / 4 / 256, blk, 0, stream>>>(xd, xd_bf);

    // 4) deltaT[d][row] = softplus(sum_r dtw[d][r]*xd[row][r] + dtb[d])  (MFMA K=64)
    gemm_mfma<4><<<dim3(ROWS / 128, DINNER / 128, 1), blk, 0, stream>>>(
        dt_proj_w, DTRANK, xd_bf, 96, deltaT, ROWS, DTRANK, 0, dt_proj_b,
        nullptr, nullptr, nullptr);

    // 5) chunk-parallel selective scan -> outzT (d-major, full-line writes)
    scan_kernel16<<<BATCH * (DINNER / 4), dim3(512), 0, stream>>>(
        deltaT, utT, xd, xzT, A_log, Dp, outzT);

    // 5b) outz = outzT^T (row-major for gemm6)
    transpose_bf16<<<dim3(ROWS / 64, DINNER / 64), blk, 0, stream>>>(
        (const ushort*)outzT, (ushort*)outz);

    // 6) out = outz @ out_proj_w^T  (MFMA split-K=2 -> f32 partials; dual-ptr B)
    gemm_mfma<2><<<dim3(DMODEL / 128, ROWS / 128, 2), blk, 0, stream>>>(
        outz, DINNER, out_proj_w, DINNER, part, DMODEL, DINNER / 2, (size_t)ROWS * DMODEL,
        nullptr, nullptr, (const bf16*)d_in[9], flag);

    // 6b) out = cvt(part0 + part1)
    sum_store<<<(ROWS * DMODEL / 4 + 255) / 256, blk, 0, stream>>>(
        part, part + (size_t)ROWS * DMODEL, d_out, flag, ROWS * DMODEL / 4);
}